// Round 1
// baseline (231.787 us; speedup 1.0000x reference)
//
#include <hip/hip_runtime.h>
#include <math.h>

// completeNet: graph-net + Sinkhorn, fully factorized.
// Sizes: T=256 tracks (nodes 0..255), M=256 dets (nodes 256..511),
// D_IN=512, D_EMB=256, E=2*65536 edges (complete bipartite, both dirs).

__device__ __forceinline__ float sigmoidf_(float x) { return 1.0f / (1.0f + expf(-x)); }

// ---------------------------------------------------------------------------
// K1: h = relu(x @ W_cnn + b_cnn)   (512x512)@(512x256)
// tiled 32x32x32, 256 threads, grid (8,16)
__global__ __launch_bounds__(256)
void k1_h(const float* __restrict__ x, const float* __restrict__ Wc,
          const float* __restrict__ bc, float* __restrict__ h) {
  __shared__ float As[32][33], Bs[32][33];
  const int tx = threadIdx.x & 31, ty = threadIdx.x >> 5;
  const int bm = blockIdx.y * 32, bn = blockIdx.x * 32;
  float acc[4] = {0.f, 0.f, 0.f, 0.f};
  for (int k0 = 0; k0 < 512; k0 += 32) {
#pragma unroll
    for (int i = 0; i < 4; ++i) {
      int idx = (int)threadIdx.x + i * 256, r = idx >> 5, c = idx & 31;
      As[r][c] = x[(bm + r) * 512 + k0 + c];
      Bs[r][c] = Wc[(k0 + r) * 256 + bn + c];
    }
    __syncthreads();
#pragma unroll
    for (int kk = 0; kk < 32; ++kk) {
      float bv = Bs[kk][tx];
#pragma unroll
      for (int i = 0; i < 4; ++i) acc[i] = fmaf(As[ty + 8 * i][kk], bv, acc[i]);
    }
    __syncthreads();
  }
  float bias = bc[bn + tx];
#pragma unroll
  for (int i = 0; i < 4; ++i) {
    float vv = acc[i] + bias;
    h[(bm + ty + 8 * i) * 256 + bn + tx] = vv > 0.f ? vv : 0.f;
  }
}

// ---------------------------------------------------------------------------
// K2: PQ[i][j] : j<128 -> P = h @ Wapp1[:256] + bapp1 ;  j>=128 -> Q = h @ Wapp1[256:]
// (bias folded into P so the edge kernel adds it exactly once)
__global__ __launch_bounds__(256)
void k2_pq(const float* __restrict__ h, const float* __restrict__ W1,
           const float* __restrict__ b1, float* __restrict__ PQ) {
  __shared__ float As[32][33], Bs[32][33];
  const int tx = threadIdx.x & 31, ty = threadIdx.x >> 5;
  const int bm = blockIdx.y * 32, bn = blockIdx.x * 32;
  const float* B = W1 + (bn >= 128 ? 256 * 128 : 0);
  const int bc0 = bn & 127;
  float acc[4] = {0.f, 0.f, 0.f, 0.f};
  for (int k0 = 0; k0 < 256; k0 += 32) {
#pragma unroll
    for (int i = 0; i < 4; ++i) {
      int idx = (int)threadIdx.x + i * 256, r = idx >> 5, c = idx & 31;
      As[r][c] = h[(bm + r) * 256 + k0 + c];
      Bs[r][c] = B[(k0 + r) * 128 + bc0 + c];
    }
    __syncthreads();
#pragma unroll
    for (int kk = 0; kk < 32; ++kk) {
      float bv = Bs[kk][tx];
#pragma unroll
      for (int i = 0; i < 4; ++i) acc[i] = fmaf(As[ty + 8 * i][kk], bv, acc[i]);
    }
    __syncthreads();
  }
  float bias = (bn < 128) ? b1[bn + tx] : 0.f;
#pragma unroll
  for (int i = 0; i < 4; ++i)
    PQ[(bm + ty + 8 * i) * 256 + bn + tx] = acc[i] + bias;
}

// ---------------------------------------------------------------------------
// K3: per-edge app/geo/e. grid 512 blocks: blocks 0..255 = half0 (s fixed),
// 256..511 = half1 (t fixed). thread d = det index 0..255.
__global__ __launch_bounds__(256)
void k3_edges(const float* __restrict__ PQ, const float* __restrict__ coords,
              const float* __restrict__ co, const float* __restrict__ Wapp2,
              const float* __restrict__ bapp2, const float* __restrict__ Wg1,
              const float* __restrict__ bg1, const float* __restrict__ Wg2,
              const float* __restrict__ bg2, const float* __restrict__ Wa1,
              const float* __restrict__ ba1, const float* __restrict__ Wa2,
              const float* __restrict__ ba2, float* __restrict__ E1,
              float* __restrict__ E2, float* __restrict__ iou1) {
  __shared__ float sFix[128], sW2[128], sWg1[256], sGfix[32], sWg2[32];
  __shared__ float sWa1[16], sBa1[8], sWa2[8];
  const int tid = threadIdx.x;
  const int half = blockIdx.x >> 8;
  const int fr = blockIdx.x & 255;
  if (tid < 128) {
    sFix[tid] = PQ[fr * 256 + (half ? 128 + tid : tid)];
    sW2[tid] = Wapp2[tid];
  }
  sWg1[tid] = Wg1[tid & 255];
  if (tid < 32) sWg2[tid] = Wg2[tid];
  if (tid < 16) sWa1[tid] = Wa1[tid];
  if (tid < 8) { sBa1[tid] = ba1[tid]; sWa2[tid] = Wa2[tid]; }
  __syncthreads();
  if (tid < 32) {
    const int offf = half ? 4 : 0;  // fixed node is src in half0, dst in half1
    float g = bg1[tid];
#pragma unroll
    for (int q = 0; q < 4; ++q) g = fmaf(coords[fr * 4 + q], sWg1[(offf + q) * 32 + tid], g);
    sGfix[tid] = g;
  }
  __syncthreads();

  const int d = tid;
  const int pnode = 256 + d;
  // app: pre = P[src] + Q[dst] (+bapp1 folded into P)
  const float* tb = PQ + pnode * 256 + (half ? 0 : 128);
  float z = 0.f;
#pragma unroll
  for (int j = 0; j < 128; j += 4) {
    float4 q4 = *reinterpret_cast<const float4*>(tb + j);
    float a;
    a = sFix[j + 0] + q4.x; a = a > 0.f ? a : 0.f; z = fmaf(a, sW2[j + 0], z);
    a = sFix[j + 1] + q4.y; a = a > 0.f ? a : 0.f; z = fmaf(a, sW2[j + 1], z);
    a = sFix[j + 2] + q4.z; a = a > 0.f ? a : 0.f; z = fmaf(a, sW2[j + 2], z);
    a = sFix[j + 3] + q4.w; a = a > 0.f ? a : 0.f; z = fmaf(a, sW2[j + 3], z);
  }
  const float app = sigmoidf_(z + bapp2[0]);
  // geo
  float4 cp = *reinterpret_cast<const float4*>(coords + pnode * 4);
  const int offp = half ? 0 : 4;
  float gz = 0.f;
#pragma unroll
  for (int m = 0; m < 32; ++m) {
    float hm = sGfix[m];
    hm = fmaf(cp.x, sWg1[(offp + 0) * 32 + m], hm);
    hm = fmaf(cp.y, sWg1[(offp + 1) * 32 + m], hm);
    hm = fmaf(cp.z, sWg1[(offp + 2) * 32 + m], hm);
    hm = fmaf(cp.w, sWg1[(offp + 3) * 32 + m], hm);
    hm = hm > 0.f ? hm : 0.f;
    gz = fmaf(hm, sWg2[m], gz);
  }
  const float geo = sigmoidf_(gz + bg2[0]);
  // e = mlp2([app, geo], Wa1(2x8), Wa2(8x1))
  float ez = 0.f;
#pragma unroll
  for (int m = 0; m < 8; ++m) {
    float hm = fmaf(app, sWa1[m], fmaf(geo, sWa1[8 + m], sBa1[m]));
    hm = hm > 0.f ? hm : 0.f;
    ez = fmaf(hm, sWa2[m], ez);
  }
  const float e = sigmoidf_(ez + ba2[0]);
  if (half == 0) {
    E1[fr * 256 + d] = e;
    float4 A4 = *reinterpret_cast<const float4*>(co + fr * 4);
    float4 B4 = *reinterpret_cast<const float4*>(co + pnode * 4);
    float ix1 = fmaxf(A4.x, B4.x), iy1 = fmaxf(A4.y, B4.y);
    float ix2 = fminf(A4.z, B4.z), iy2 = fminf(A4.w, B4.w);
    float inter = fmaxf(ix2 - ix1, 0.f) * fmaxf(iy2 - iy1, 0.f);
    float areaA = (A4.z - A4.x) * (A4.w - A4.y);
    float areaB = (B4.z - B4.x) * (B4.w - B4.y);
    iou1[fr * 256 + d] = inter / (areaA + areaB - inter + 1e-8f);
  } else {
    E2[fr * 256 + d] = e;
  }
}

// ---------------------------------------------------------------------------
// K4: agg. grid (8,8,2): z=0: agg[0:256] = E2 @ H_det ; z=1: agg[256:512] = E1^T @ H_track
__global__ __launch_bounds__(256)
void k4_agg(const float* __restrict__ E1, const float* __restrict__ E2,
            const float* __restrict__ h, float* __restrict__ agg) {
  __shared__ float As[32][33], Bs[32][33];
  const int tx = threadIdx.x & 31, ty = threadIdx.x >> 5;
  const int bm = blockIdx.y * 32, bn = blockIdx.x * 32;
  const int zt = blockIdx.z;
  float acc[4] = {0.f, 0.f, 0.f, 0.f};
  for (int k0 = 0; k0 < 256; k0 += 32) {
#pragma unroll
    for (int i = 0; i < 4; ++i) {
      int idx = (int)threadIdx.x + i * 256, r = idx >> 5, c = idx & 31;
      if (zt == 0) {
        As[r][c] = E2[(bm + r) * 256 + k0 + c];
        Bs[r][c] = h[(256 + k0 + r) * 256 + bn + c];
      } else {
        As[r][c] = E1[(k0 + r) * 256 + bm + c];  // As[k_local][m_local]
        Bs[r][c] = h[(k0 + r) * 256 + bn + c];
      }
    }
    __syncthreads();
    if (zt == 0) {
#pragma unroll
      for (int kk = 0; kk < 32; ++kk) {
        float bv = Bs[kk][tx];
#pragma unroll
        for (int i = 0; i < 4; ++i) acc[i] = fmaf(As[ty + 8 * i][kk], bv, acc[i]);
      }
    } else {
#pragma unroll
      for (int kk = 0; kk < 32; ++kk) {
        float bv = Bs[kk][tx];
#pragma unroll
        for (int i = 0; i < 4; ++i) acc[i] = fmaf(As[kk][ty + 8 * i], bv, acc[i]);
      }
    }
    __syncthreads();
  }
  float* C = agg + zt * 65536;
#pragma unroll
  for (int i = 0; i < 4; ++i) C[(bm + ty + 8 * i) * 256 + bn + tx] = acc[i];
}

// ---------------------------------------------------------------------------
// K5: out = relu(h @ Wo1 + agg @ Wo2 + bo)  (dual-A GEMM, K=512 switch at 256)
__global__ __launch_bounds__(256)
void k5_out(const float* __restrict__ h, const float* __restrict__ agg,
            const float* __restrict__ Wo1, const float* __restrict__ Wo2,
            const float* __restrict__ bo, float* __restrict__ outm) {
  __shared__ float As[32][33], Bs[32][33];
  const int tx = threadIdx.x & 31, ty = threadIdx.x >> 5;
  const int bm = blockIdx.y * 32, bn = blockIdx.x * 32;
  float acc[4] = {0.f, 0.f, 0.f, 0.f};
  for (int k0 = 0; k0 < 512; k0 += 32) {
    const float* A = (k0 < 256) ? h : agg;
    const float* B = (k0 < 256) ? Wo1 : Wo2;
    const int ka = k0 & 255;
#pragma unroll
    for (int i = 0; i < 4; ++i) {
      int idx = (int)threadIdx.x + i * 256, r = idx >> 5, c = idx & 31;
      As[r][c] = A[(bm + r) * 256 + ka + c];
      Bs[r][c] = B[(ka + r) * 256 + bn + c];
    }
    __syncthreads();
#pragma unroll
    for (int kk = 0; kk < 32; ++kk) {
      float bv = Bs[kk][tx];
#pragma unroll
      for (int i = 0; i < 4; ++i) acc[i] = fmaf(As[ty + 8 * i][kk], bv, acc[i]);
    }
    __syncthreads();
  }
  float bias = bo[bn + tx];
#pragma unroll
  for (int i = 0; i < 4; ++i) {
    float vv = acc[i] + bias;
    outm[(bm + ty + 8 * i) * 256 + bn + tx] = vv > 0.f ? vv : 0.f;
  }
}

// ---------------------------------------------------------------------------
// K5b: row norms n[i] = max(||out[i]||, 1e-6). one wave per row.
__global__ __launch_bounds__(256)
void k5b_norm(const float* __restrict__ outm, float* __restrict__ nrm) {
  const int lane = threadIdx.x & 63;
  const int row = blockIdx.x * 4 + (threadIdx.x >> 6);
  float4 v4 = *reinterpret_cast<const float4*>(outm + row * 256 + lane * 4);
  float s = v4.x * v4.x + v4.y * v4.y + v4.z * v4.z + v4.w * v4.w;
#pragma unroll
  for (int m = 32; m; m >>= 1) s += __shfl_xor(s, m, 64);
  if (lane == 0) nrm[row] = fmaxf(sqrtf(s), 1e-6f);
}

// ---------------------------------------------------------------------------
// K6: cos + final score MLP -> M[257][257] = exp(5*score) (+slack), and M^T.
// grid 257 blocks; block s<256 handles row s, block 256 fills slack row.
__global__ __launch_bounds__(256)
void k6_score(const float* __restrict__ outm, const float* __restrict__ nrm,
              const float* __restrict__ iou1, const float* __restrict__ Wf1,
              const float* __restrict__ bf1, const float* __restrict__ Wf2,
              const float* __restrict__ bf2, float* __restrict__ Mm,
              float* __restrict__ MT) {
  const int tid = threadIdx.x;
  const int s = blockIdx.x;
  const float slack = expf(1.0f);  // exp(LAM*SLACK) = exp(5*0.2)
  if (s == 256) {
    for (int c = tid; c < 257; c += 256) {
      Mm[256 * 257 + c] = slack;
      MT[c * 257 + 256] = slack;
    }
    return;
  }
  __shared__ float so[256];
  so[tid] = outm[s * 256 + tid];
  __syncthreads();
  const float* od = outm + (256 + tid) * 256;
  float dot = 0.f;
#pragma unroll 8
  for (int j = 0; j < 256; j += 4) {
    float4 o4 = *reinterpret_cast<const float4*>(od + j);
    dot = fmaf(so[j + 0], o4.x, dot);
    dot = fmaf(so[j + 1], o4.y, dot);
    dot = fmaf(so[j + 2], o4.z, dot);
    dot = fmaf(so[j + 3], o4.w, dot);
  }
  const float cosv = dot / (nrm[s] * nrm[256 + tid]);
  const float i1 = iou1[s * 256 + tid];
  float sz = 0.f;
#pragma unroll
  for (int m = 0; m < 8; ++m) {
    float hm = fmaf(cosv, Wf1[m], fmaf(i1, Wf1[8 + m], bf1[m]));
    hm = hm > 0.f ? hm : 0.f;
    sz = fmaf(hm, Wf2[m], sz);
  }
  const float score = sigmoidf_(sz + bf2[0]);
  const float mv = expf(5.0f * score);
  Mm[s * 257 + tid] = mv;
  MT[tid * 257 + s] = mv;
  if (tid == 0) {
    Mm[s * 257 + 256] = slack;
    MT[256 * 257 + s] = slack;
  }
}

// ---------------------------------------------------------------------------
// K7: Sinkhorn via diagonal scaling: u = 1/(M v), v = 1/(M^T u), 8 iters.
// Single kernel, 32 co-resident blocks, device-scope atomic grid barrier.
__device__ __forceinline__ float aload(const float* p) {
  return __hip_atomic_load(p, __ATOMIC_RELAXED, __HIP_MEMORY_SCOPE_AGENT);
}
__device__ __forceinline__ void astore(float* p, float v) {
  __hip_atomic_store(p, v, __ATOMIC_RELAXED, __HIP_MEMORY_SCOPE_AGENT);
}
__device__ __forceinline__ void grid_sync(unsigned* bar, unsigned target) {
  __syncthreads();
  if (threadIdx.x == 0) {
    __threadfence();
    __hip_atomic_fetch_add(bar, 1u, __ATOMIC_ACQ_REL, __HIP_MEMORY_SCOPE_AGENT);
    while (__hip_atomic_load(bar, __ATOMIC_ACQUIRE, __HIP_MEMORY_SCOPE_AGENT) < target) {
      __builtin_amdgcn_s_sleep(2);
    }
    __threadfence();
  }
  __syncthreads();
}

__global__ __launch_bounds__(256)
void k7_sink(const float* __restrict__ Mm, const float* __restrict__ MT,
             float* __restrict__ u, float* __restrict__ v,
             float* __restrict__ outp, unsigned* __restrict__ bar) {
  const int lane = threadIdx.x & 63;
  const int wid = (blockIdx.x << 2) + (threadIdx.x >> 6);  // 0..127
  for (int p = 0; p < 16; ++p) {
    const float* Mx = (p & 1) ? MT : Mm;
    const float* inv = (p & 1) ? u : v;
    float* outv = (p & 1) ? v : u;
    for (int r = wid; r < 257; r += 128) {
      const float* row = Mx + r * 257;
      float sum = 0.f;
      for (int c = lane; c < 257; c += 64) {
        float mval = row[c];
        sum += (p == 0) ? mval : mval * aload(inv + c);
      }
#pragma unroll
      for (int m = 32; m; m >>= 1) sum += __shfl_xor(sum, m, 64);
      if (lane == 0) astore(outv + r, 1.0f / sum);
    }
    grid_sync(bar, 32u * (unsigned)(p + 1));
  }
  // final: mat[s][d] = u[s] * M[s][d] * v[d], top-left 256x256, flattened
  for (int idx = blockIdx.x * 256 + threadIdx.x; idx < 65536; idx += 32 * 256) {
    const int s = idx >> 8, d = idx & 255;
    outp[idx] = aload(u + s) * Mm[s * 257 + d] * aload(v + d);
  }
}

// ---------------------------------------------------------------------------
extern "C" void kernel_launch(void* const* d_in, const int* in_sizes, int n_in,
                              void* d_out, int out_size, void* d_ws, size_t ws_size,
                              hipStream_t stream) {
  (void)in_sizes; (void)n_in; (void)out_size; (void)ws_size;
  const float* x      = (const float*)d_in[0];
  const float* coords = (const float*)d_in[1];
  const float* co     = (const float*)d_in[2];
  // d_in[3] = edge_index (int32) — structure is deterministic, not needed
  const float* Wc    = (const float*)d_in[4];
  const float* bc    = (const float*)d_in[5];
  const float* Wapp1 = (const float*)d_in[6];
  const float* bapp1 = (const float*)d_in[7];
  const float* Wapp2 = (const float*)d_in[8];
  const float* bapp2 = (const float*)d_in[9];
  const float* Wg1   = (const float*)d_in[10];
  const float* bg1   = (const float*)d_in[11];
  const float* Wg2   = (const float*)d_in[12];
  const float* bg2   = (const float*)d_in[13];
  const float* Wa1   = (const float*)d_in[14];
  const float* ba1   = (const float*)d_in[15];
  const float* Wa2   = (const float*)d_in[16];
  const float* ba2   = (const float*)d_in[17];
  const float* Wo1   = (const float*)d_in[18];
  const float* Wo2   = (const float*)d_in[19];
  const float* bo    = (const float*)d_in[20];
  const float* Wf1   = (const float*)d_in[21];
  const float* bf1   = (const float*)d_in[22];
  const float* Wf2   = (const float*)d_in[23];
  const float* bf2   = (const float*)d_in[24];

  float* ws   = (float*)d_ws;
  float* h    = ws + 0;        // 512*256
  float* PQ   = ws + 131072;   // 512*256
  float* E1   = ws + 262144;   // 256*256
  float* E2   = ws + 327680;   // 256*256
  float* iou1 = ws + 393216;   // 256*256
  float* agg  = ws + 458752;   // 512*256
  float* outm = ws + 589824;   // 512*256
  float* nrm  = ws + 720896;   // 512
  float* Mm   = ws + 721408;   // 257*257 (padded slot 66560)
  float* MT   = ws + 787968;   // 257*257 (padded)
  float* u    = ws + 854528;   // 257 (padded 264)
  float* v    = ws + 854792;   // 257 (padded 264)
  unsigned* bar = (unsigned*)(ws + 855056);

  hipMemsetAsync(bar, 0, sizeof(unsigned), stream);

  k1_h<<<dim3(8, 16), 256, 0, stream>>>(x, Wc, bc, h);
  k2_pq<<<dim3(8, 16), 256, 0, stream>>>(h, Wapp1, bapp1, PQ);
  k3_edges<<<512, 256, 0, stream>>>(PQ, coords, co, Wapp2, bapp2, Wg1, bg1, Wg2,
                                    bg2, Wa1, ba1, Wa2, ba2, E1, E2, iou1);
  k4_agg<<<dim3(8, 8, 2), 256, 0, stream>>>(E1, E2, h, agg);
  k5_out<<<dim3(8, 16), 256, 0, stream>>>(h, agg, Wo1, Wo2, bo, outm);
  k5b_norm<<<128, 256, 0, stream>>>(outm, nrm);
  k6_score<<<257, 256, 0, stream>>>(outm, nrm, iou1, Wf1, bf1, Wf2, bf2, Mm, MT);
  k7_sink<<<32, 256, 0, stream>>>(Mm, MT, u, v, (float*)d_out, bar);
}

// Round 2
// 213.731 us; speedup vs baseline: 1.0845x; 1.0845x over previous
//
#include <hip/hip_runtime.h>
#include <math.h>

// completeNet: graph-net + Sinkhorn, fully factorized.
// Sizes: T=256 tracks (nodes 0..255), M=256 dets (nodes 256..511),
// D_IN=512, D_EMB=256, E=2*65536 edges (complete bipartite, both dirs).

__device__ __forceinline__ float sigmoidf_(float x) { return 1.0f / (1.0f + expf(-x)); }

// ---------------------------------------------------------------------------
// K1: h = relu(x @ W_cnn + b_cnn)   (512x512)@(512x256)
__global__ __launch_bounds__(256)
void k1_h(const float* __restrict__ x, const float* __restrict__ Wc,
          const float* __restrict__ bc, float* __restrict__ h) {
  __shared__ float As[32][33], Bs[32][33];
  const int tx = threadIdx.x & 31, ty = threadIdx.x >> 5;
  const int bm = blockIdx.y * 32, bn = blockIdx.x * 32;
  float acc[4] = {0.f, 0.f, 0.f, 0.f};
  for (int k0 = 0; k0 < 512; k0 += 32) {
#pragma unroll
    for (int i = 0; i < 4; ++i) {
      int idx = (int)threadIdx.x + i * 256, r = idx >> 5, c = idx & 31;
      As[r][c] = x[(bm + r) * 512 + k0 + c];
      Bs[r][c] = Wc[(k0 + r) * 256 + bn + c];
    }
    __syncthreads();
#pragma unroll
    for (int kk = 0; kk < 32; ++kk) {
      float bv = Bs[kk][tx];
#pragma unroll
      for (int i = 0; i < 4; ++i) acc[i] = fmaf(As[ty + 8 * i][kk], bv, acc[i]);
    }
    __syncthreads();
  }
  float bias = bc[bn + tx];
#pragma unroll
  for (int i = 0; i < 4; ++i) {
    float vv = acc[i] + bias;
    h[(bm + ty + 8 * i) * 256 + bn + tx] = vv > 0.f ? vv : 0.f;
  }
}

// ---------------------------------------------------------------------------
// K2: PQ[i][j] : j<128 -> P = h @ Wapp1[:256] + bapp1 ;  j>=128 -> Q = h @ Wapp1[256:]
__global__ __launch_bounds__(256)
void k2_pq(const float* __restrict__ h, const float* __restrict__ W1,
           const float* __restrict__ b1, float* __restrict__ PQ) {
  __shared__ float As[32][33], Bs[32][33];
  const int tx = threadIdx.x & 31, ty = threadIdx.x >> 5;
  const int bm = blockIdx.y * 32, bn = blockIdx.x * 32;
  const float* B = W1 + (bn >= 128 ? 256 * 128 : 0);
  const int bc0 = bn & 127;
  float acc[4] = {0.f, 0.f, 0.f, 0.f};
  for (int k0 = 0; k0 < 256; k0 += 32) {
#pragma unroll
    for (int i = 0; i < 4; ++i) {
      int idx = (int)threadIdx.x + i * 256, r = idx >> 5, c = idx & 31;
      As[r][c] = h[(bm + r) * 256 + k0 + c];
      Bs[r][c] = B[(k0 + r) * 128 + bc0 + c];
    }
    __syncthreads();
#pragma unroll
    for (int kk = 0; kk < 32; ++kk) {
      float bv = Bs[kk][tx];
#pragma unroll
      for (int i = 0; i < 4; ++i) acc[i] = fmaf(As[ty + 8 * i][kk], bv, acc[i]);
    }
    __syncthreads();
  }
  float bias = (bn < 128) ? b1[bn + tx] : 0.f;
#pragma unroll
  for (int i = 0; i < 4; ++i)
    PQ[(bm + ty + 8 * i) * 256 + bn + tx] = acc[i] + bias;
}

// ---------------------------------------------------------------------------
// K3: per-edge app/geo/e. blocks 0..255 = half0 (s fixed), 256..511 = half1.
__global__ __launch_bounds__(256)
void k3_edges(const float* __restrict__ PQ, const float* __restrict__ coords,
              const float* __restrict__ co, const float* __restrict__ Wapp2,
              const float* __restrict__ bapp2, const float* __restrict__ Wg1,
              const float* __restrict__ bg1, const float* __restrict__ Wg2,
              const float* __restrict__ bg2, const float* __restrict__ Wa1,
              const float* __restrict__ ba1, const float* __restrict__ Wa2,
              const float* __restrict__ ba2, float* __restrict__ E1,
              float* __restrict__ E2, float* __restrict__ iou1) {
  __shared__ float sFix[128], sW2[128], sWg1[256], sGfix[32], sWg2[32];
  __shared__ float sWa1[16], sBa1[8], sWa2[8];
  const int tid = threadIdx.x;
  const int half = blockIdx.x >> 8;
  const int fr = blockIdx.x & 255;
  if (tid < 128) {
    sFix[tid] = PQ[fr * 256 + (half ? 128 + tid : tid)];
    sW2[tid] = Wapp2[tid];
  }
  sWg1[tid] = Wg1[tid & 255];
  if (tid < 32) sWg2[tid] = Wg2[tid];
  if (tid < 16) sWa1[tid] = Wa1[tid];
  if (tid < 8) { sBa1[tid] = ba1[tid]; sWa2[tid] = Wa2[tid]; }
  __syncthreads();
  if (tid < 32) {
    const int offf = half ? 4 : 0;
    float g = bg1[tid];
#pragma unroll
    for (int q = 0; q < 4; ++q) g = fmaf(coords[fr * 4 + q], sWg1[(offf + q) * 32 + tid], g);
    sGfix[tid] = g;
  }
  __syncthreads();

  const int d = tid;
  const int pnode = 256 + d;
  const float* tb = PQ + pnode * 256 + (half ? 0 : 128);
  float z = 0.f;
#pragma unroll
  for (int j = 0; j < 128; j += 4) {
    float4 q4 = *reinterpret_cast<const float4*>(tb + j);
    float a;
    a = sFix[j + 0] + q4.x; a = a > 0.f ? a : 0.f; z = fmaf(a, sW2[j + 0], z);
    a = sFix[j + 1] + q4.y; a = a > 0.f ? a : 0.f; z = fmaf(a, sW2[j + 1], z);
    a = sFix[j + 2] + q4.z; a = a > 0.f ? a : 0.f; z = fmaf(a, sW2[j + 2], z);
    a = sFix[j + 3] + q4.w; a = a > 0.f ? a : 0.f; z = fmaf(a, sW2[j + 3], z);
  }
  const float app = sigmoidf_(z + bapp2[0]);
  float4 cp = *reinterpret_cast<const float4*>(coords + pnode * 4);
  const int offp = half ? 0 : 4;
  float gz = 0.f;
#pragma unroll
  for (int m = 0; m < 32; ++m) {
    float hm = sGfix[m];
    hm = fmaf(cp.x, sWg1[(offp + 0) * 32 + m], hm);
    hm = fmaf(cp.y, sWg1[(offp + 1) * 32 + m], hm);
    hm = fmaf(cp.z, sWg1[(offp + 2) * 32 + m], hm);
    hm = fmaf(cp.w, sWg1[(offp + 3) * 32 + m], hm);
    hm = hm > 0.f ? hm : 0.f;
    gz = fmaf(hm, sWg2[m], gz);
  }
  const float geo = sigmoidf_(gz + bg2[0]);
  float ez = 0.f;
#pragma unroll
  for (int m = 0; m < 8; ++m) {
    float hm = fmaf(app, sWa1[m], fmaf(geo, sWa1[8 + m], sBa1[m]));
    hm = hm > 0.f ? hm : 0.f;
    ez = fmaf(hm, sWa2[m], ez);
  }
  const float e = sigmoidf_(ez + ba2[0]);
  if (half == 0) {
    E1[fr * 256 + d] = e;
    float4 A4 = *reinterpret_cast<const float4*>(co + fr * 4);
    float4 B4 = *reinterpret_cast<const float4*>(co + pnode * 4);
    float ix1 = fmaxf(A4.x, B4.x), iy1 = fmaxf(A4.y, B4.y);
    float ix2 = fminf(A4.z, B4.z), iy2 = fminf(A4.w, B4.w);
    float inter = fmaxf(ix2 - ix1, 0.f) * fmaxf(iy2 - iy1, 0.f);
    float areaA = (A4.z - A4.x) * (A4.w - A4.y);
    float areaB = (B4.z - B4.x) * (B4.w - B4.y);
    iou1[fr * 256 + d] = inter / (areaA + areaB - inter + 1e-8f);
  } else {
    E2[fr * 256 + d] = e;
  }
}

// ---------------------------------------------------------------------------
// K4: agg. z=0: agg[0:256] = E2 @ H_det ; z=1: agg[256:512] = E1^T @ H_track
__global__ __launch_bounds__(256)
void k4_agg(const float* __restrict__ E1, const float* __restrict__ E2,
            const float* __restrict__ h, float* __restrict__ agg) {
  __shared__ float As[32][33], Bs[32][33];
  const int tx = threadIdx.x & 31, ty = threadIdx.x >> 5;
  const int bm = blockIdx.y * 32, bn = blockIdx.x * 32;
  const int zt = blockIdx.z;
  float acc[4] = {0.f, 0.f, 0.f, 0.f};
  for (int k0 = 0; k0 < 256; k0 += 32) {
#pragma unroll
    for (int i = 0; i < 4; ++i) {
      int idx = (int)threadIdx.x + i * 256, r = idx >> 5, c = idx & 31;
      if (zt == 0) {
        As[r][c] = E2[(bm + r) * 256 + k0 + c];
        Bs[r][c] = h[(256 + k0 + r) * 256 + bn + c];
      } else {
        As[r][c] = E1[(k0 + r) * 256 + bm + c];
        Bs[r][c] = h[(k0 + r) * 256 + bn + c];
      }
    }
    __syncthreads();
    if (zt == 0) {
#pragma unroll
      for (int kk = 0; kk < 32; ++kk) {
        float bv = Bs[kk][tx];
#pragma unroll
        for (int i = 0; i < 4; ++i) acc[i] = fmaf(As[ty + 8 * i][kk], bv, acc[i]);
      }
    } else {
#pragma unroll
      for (int kk = 0; kk < 32; ++kk) {
        float bv = Bs[kk][tx];
#pragma unroll
        for (int i = 0; i < 4; ++i) acc[i] = fmaf(As[kk][ty + 8 * i], bv, acc[i]);
      }
    }
    __syncthreads();
  }
  float* C = agg + zt * 65536;
#pragma unroll
  for (int i = 0; i < 4; ++i) C[(bm + ty + 8 * i) * 256 + bn + tx] = acc[i];
}

// ---------------------------------------------------------------------------
// K5: out = relu(h @ Wo1 + agg @ Wo2 + bo)
__global__ __launch_bounds__(256)
void k5_out(const float* __restrict__ h, const float* __restrict__ agg,
            const float* __restrict__ Wo1, const float* __restrict__ Wo2,
            const float* __restrict__ bo, float* __restrict__ outm) {
  __shared__ float As[32][33], Bs[32][33];
  const int tx = threadIdx.x & 31, ty = threadIdx.x >> 5;
  const int bm = blockIdx.y * 32, bn = blockIdx.x * 32;
  float acc[4] = {0.f, 0.f, 0.f, 0.f};
  for (int k0 = 0; k0 < 512; k0 += 32) {
    const float* A = (k0 < 256) ? h : agg;
    const float* B = (k0 < 256) ? Wo1 : Wo2;
    const int ka = k0 & 255;
#pragma unroll
    for (int i = 0; i < 4; ++i) {
      int idx = (int)threadIdx.x + i * 256, r = idx >> 5, c = idx & 31;
      As[r][c] = A[(bm + r) * 256 + ka + c];
      Bs[r][c] = B[(ka + r) * 256 + bn + c];
    }
    __syncthreads();
#pragma unroll
    for (int kk = 0; kk < 32; ++kk) {
      float bv = Bs[kk][tx];
#pragma unroll
      for (int i = 0; i < 4; ++i) acc[i] = fmaf(As[ty + 8 * i][kk], bv, acc[i]);
    }
    __syncthreads();
  }
  float bias = bo[bn + tx];
#pragma unroll
  for (int i = 0; i < 4; ++i) {
    float vv = acc[i] + bias;
    outm[(bm + ty + 8 * i) * 256 + bn + tx] = vv > 0.f ? vv : 0.f;
  }
}

// ---------------------------------------------------------------------------
// K5b: row norms n[i] = max(||out[i]||, 1e-6). one wave per row.
__global__ __launch_bounds__(256)
void k5b_norm(const float* __restrict__ outm, float* __restrict__ nrm) {
  const int lane = threadIdx.x & 63;
  const int row = blockIdx.x * 4 + (threadIdx.x >> 6);
  float4 v4 = *reinterpret_cast<const float4*>(outm + row * 256 + lane * 4);
  float s = v4.x * v4.x + v4.y * v4.y + v4.z * v4.z + v4.w * v4.w;
#pragma unroll
  for (int m = 32; m; m >>= 1) s += __shfl_xor(s, m, 64);
  if (lane == 0) nrm[row] = fmaxf(sqrtf(s), 1e-6f);
}

// ---------------------------------------------------------------------------
// K6: cos + final score MLP -> Mblk[256][256] = exp(5*score). (slack row/col
// of the Sinkhorn matrix is a compile-time constant, handled in k7.)
__global__ __launch_bounds__(256)
void k6_score(const float* __restrict__ outm, const float* __restrict__ nrm,
              const float* __restrict__ iou1, const float* __restrict__ Wf1,
              const float* __restrict__ bf1, const float* __restrict__ Wf2,
              const float* __restrict__ bf2, float* __restrict__ Mblk) {
  const int tid = threadIdx.x;
  const int s = blockIdx.x;
  __shared__ float so[256];
  so[tid] = outm[s * 256 + tid];
  __syncthreads();
  const float* od = outm + (256 + tid) * 256;
  float dot = 0.f;
#pragma unroll 8
  for (int j = 0; j < 256; j += 4) {
    float4 o4 = *reinterpret_cast<const float4*>(od + j);
    dot = fmaf(so[j + 0], o4.x, dot);
    dot = fmaf(so[j + 1], o4.y, dot);
    dot = fmaf(so[j + 2], o4.z, dot);
    dot = fmaf(so[j + 3], o4.w, dot);
  }
  const float cosv = dot / (nrm[s] * nrm[256 + tid]);
  const float i1 = iou1[s * 256 + tid];
  float sz = 0.f;
#pragma unroll
  for (int m = 0; m < 8; ++m) {
    float hm = fmaf(cosv, Wf1[m], fmaf(i1, Wf1[8 + m], bf1[m]));
    hm = hm > 0.f ? hm : 0.f;
    sz = fmaf(hm, Wf2[m], sz);
  }
  const float score = sigmoidf_(sz + bf2[0]);
  Mblk[s * 256 + tid] = expf(5.0f * score);
}

// ---------------------------------------------------------------------------
// K7: Sinkhorn, single 1024-thread block, no grid sync.
// mat_k = diag(u) M diag(v); u = 1/(M v), v = 1/(M^T u), 8 iters.
// M = [Mblk, slack; slack, slack] (257x257). Rows 0..127 of Mblk staged in LDS.
// Row pass: wave-per-row, float4 coalesced. Col pass: thread-per-col, coalesced.
__global__ __launch_bounds__(1024)
void k7_sink(const float* __restrict__ Mg, float* __restrict__ outp) {
  __shared__ float Ms[32768];  // 128 KiB: rows 0..127 of Mblk
  __shared__ float su[257], sv[257];
  __shared__ float psum[4][256];
  const int tid = threadIdx.x;
  const int w = tid >> 6, lane = tid & 63;
  const float slack = expf(1.0f);  // exp(LAM*SLACK) = exp(5*0.2)
  for (int i = tid * 4; i < 32768; i += 4096)
    *reinterpret_cast<float4*>(&Ms[i]) = *reinterpret_cast<const float4*>(&Mg[i]);
  if (tid < 257) sv[tid] = 1.0f;
  __syncthreads();
  for (int it = 0; it < 8; ++it) {
    // -------- row pass: su[r] = 1/(sum_c M[r][c]*sv[c] + slack*sv[256])
    const float4 v4 = *reinterpret_cast<const float4*>(&sv[lane * 4]);
    const float sv256 = sv[256];
    float part[16];
    if (w < 8) {
#pragma unroll
      for (int rr = 0; rr < 16; ++rr) {
        const float4 m4 =
            *reinterpret_cast<const float4*>(&Ms[((w << 4) + rr) * 256 + lane * 4]);
        part[rr] = m4.x * v4.x + m4.y * v4.y + m4.z * v4.z + m4.w * v4.w;
      }
    } else {
#pragma unroll
      for (int rr = 0; rr < 16; ++rr) {
        const float4 m4 =
            *reinterpret_cast<const float4*>(&Mg[((w << 4) + rr) * 256 + lane * 4]);
        part[rr] = m4.x * v4.x + m4.y * v4.y + m4.z * v4.z + m4.w * v4.w;
      }
    }
#pragma unroll
    for (int rr = 0; rr < 16; ++rr) {
      float s = part[rr];
#pragma unroll
      for (int m = 32; m; m >>= 1) s += __shfl_xor(s, m, 64);
      if (lane == 0) su[(w << 4) + rr] = 1.0f / (s + slack * sv256);
    }
    if (w == 0) {  // slack row: su[256] = 1/(slack * sum(sv))
      float s = sv[lane] + sv[lane + 64] + sv[lane + 128] + sv[lane + 192] +
                (lane == 0 ? sv[256] : 0.f);
#pragma unroll
      for (int m = 32; m; m >>= 1) s += __shfl_xor(s, m, 64);
      if (lane == 0) su[256] = 1.0f / (slack * s);
    }
    __syncthreads();
    // -------- col pass: sv[c] = 1/(sum_r M[r][c]*su[r] + slack*su[256])
    const int g = tid >> 8, c = tid & 255;
    float ps = 0.f;
    for (int r = g; r < 128; r += 4) ps += Ms[r * 256 + c] * su[r];
    for (int r = 128 + g; r < 256; r += 4) ps += Mg[r * 256 + c] * su[r];
    psum[g][c] = ps;
    float usum = 0.f;
    if (w == 4) {  // slack col: needs sum(su)
      float s = su[lane] + su[lane + 64] + su[lane + 128] + su[lane + 192] +
                (lane == 0 ? su[256] : 0.f);
#pragma unroll
      for (int m = 32; m; m >>= 1) s += __shfl_xor(s, m, 64);
      usum = s;
    }
    __syncthreads();
    const float su256 = su[256];
    if (tid < 256)
      sv[tid] = 1.0f / (psum[0][tid] + psum[1][tid] + psum[2][tid] +
                        psum[3][tid] + slack * su256);
    if (tid == 256) sv[256] = 1.0f / (slack * usum);
    __syncthreads();
  }
  // -------- output: out[r][c] = su[r] * M[r][c] * sv[c]
  for (int b = tid * 4; b < 65536; b += 4096) {
    const int r = b >> 8, c = b & 255;
    const float4 m4 = (r < 128) ? *reinterpret_cast<const float4*>(&Ms[b])
                                : *reinterpret_cast<const float4*>(&Mg[b]);
    const float4 vv = *reinterpret_cast<const float4*>(&sv[c]);
    const float ur = su[r];
    float4 o;
    o.x = ur * m4.x * vv.x;
    o.y = ur * m4.y * vv.y;
    o.z = ur * m4.z * vv.z;
    o.w = ur * m4.w * vv.w;
    *reinterpret_cast<float4*>(&outp[b]) = o;
  }
}

// ---------------------------------------------------------------------------
extern "C" void kernel_launch(void* const* d_in, const int* in_sizes, int n_in,
                              void* d_out, int out_size, void* d_ws, size_t ws_size,
                              hipStream_t stream) {
  (void)in_sizes; (void)n_in; (void)out_size; (void)ws_size;
  const float* x      = (const float*)d_in[0];
  const float* coords = (const float*)d_in[1];
  const float* co     = (const float*)d_in[2];
  // d_in[3] = edge_index (int32) — structure is deterministic, not needed
  const float* Wc    = (const float*)d_in[4];
  const float* bc    = (const float*)d_in[5];
  const float* Wapp1 = (const float*)d_in[6];
  const float* bapp1 = (const float*)d_in[7];
  const float* Wapp2 = (const float*)d_in[8];
  const float* bapp2 = (const float*)d_in[9];
  const float* Wg1   = (const float*)d_in[10];
  const float* bg1   = (const float*)d_in[11];
  const float* Wg2   = (const float*)d_in[12];
  const float* bg2   = (const float*)d_in[13];
  const float* Wa1   = (const float*)d_in[14];
  const float* ba1   = (const float*)d_in[15];
  const float* Wa2   = (const float*)d_in[16];
  const float* ba2   = (const float*)d_in[17];
  const float* Wo1   = (const float*)d_in[18];
  const float* Wo2   = (const float*)d_in[19];
  const float* bo    = (const float*)d_in[20];
  const float* Wf1   = (const float*)d_in[21];
  const float* bf1   = (const float*)d_in[22];
  const float* Wf2   = (const float*)d_in[23];
  const float* bf2   = (const float*)d_in[24];

  float* ws   = (float*)d_ws;
  float* h    = ws + 0;        // 512*256
  float* PQ   = ws + 131072;   // 512*256
  float* E1   = ws + 262144;   // 256*256
  float* E2   = ws + 327680;   // 256*256
  float* iou1 = ws + 393216;   // 256*256
  float* agg  = ws + 458752;   // 512*256
  float* outm = ws + 589824;   // 512*256
  float* nrm  = ws + 720896;   // 512
  float* Mblk = ws + 721408;   // 256*256

  k1_h<<<dim3(8, 16), 256, 0, stream>>>(x, Wc, bc, h);
  k2_pq<<<dim3(8, 16), 256, 0, stream>>>(h, Wapp1, bapp1, PQ);
  k3_edges<<<512, 256, 0, stream>>>(PQ, coords, co, Wapp2, bapp2, Wg1, bg1, Wg2,
                                    bg2, Wa1, ba1, Wa2, ba2, E1, E2, iou1);
  k4_agg<<<dim3(8, 8, 2), 256, 0, stream>>>(E1, E2, h, agg);
  k5_out<<<dim3(8, 16), 256, 0, stream>>>(h, agg, Wo1, Wo2, bo, outm);
  k5b_norm<<<128, 256, 0, stream>>>(outm, nrm);
  k6_score<<<256, 256, 0, stream>>>(outm, nrm, iou1, Wf1, bf1, Wf2, bf2, Mblk);
  k7_sink<<<1, 1024, 0, stream>>>(Mblk, (float*)d_out);
}

// Round 3
// 160.861 us; speedup vs baseline: 1.4409x; 1.3287x over previous
//
#include <hip/hip_runtime.h>
#include <hip/hip_fp16.h>
#include <math.h>

// completeNet: graph-net + Sinkhorn, fully factorized.
// Sizes: T=256 tracks (nodes 0..255), M=256 dets (nodes 256..511),
// D_IN=512, D_EMB=256, E=2*65536 edges (complete bipartite, both dirs).

__device__ __forceinline__ float sigmoidf_(float x) { return 1.0f / (1.0f + expf(-x)); }

// ---------------------------------------------------------------------------
// K1: h = relu(x @ W_cnn + b_cnn)   (512x512)@(512x256)
__global__ __launch_bounds__(256)
void k1_h(const float* __restrict__ x, const float* __restrict__ Wc,
          const float* __restrict__ bc, float* __restrict__ h) {
  __shared__ float As[32][33], Bs[32][33];
  const int tx = threadIdx.x & 31, ty = threadIdx.x >> 5;
  const int bm = blockIdx.y * 32, bn = blockIdx.x * 32;
  float acc[4] = {0.f, 0.f, 0.f, 0.f};
  for (int k0 = 0; k0 < 512; k0 += 32) {
#pragma unroll
    for (int i = 0; i < 4; ++i) {
      int idx = (int)threadIdx.x + i * 256, r = idx >> 5, c = idx & 31;
      As[r][c] = x[(bm + r) * 512 + k0 + c];
      Bs[r][c] = Wc[(k0 + r) * 256 + bn + c];
    }
    __syncthreads();
#pragma unroll
    for (int kk = 0; kk < 32; ++kk) {
      float bv = Bs[kk][tx];
#pragma unroll
      for (int i = 0; i < 4; ++i) acc[i] = fmaf(As[ty + 8 * i][kk], bv, acc[i]);
    }
    __syncthreads();
  }
  float bias = bc[bn + tx];
#pragma unroll
  for (int i = 0; i < 4; ++i) {
    float vv = acc[i] + bias;
    h[(bm + ty + 8 * i) * 256 + bn + tx] = vv > 0.f ? vv : 0.f;
  }
}

// ---------------------------------------------------------------------------
// K2: PQ[i][j] : j<128 -> P = h @ Wapp1[:256] + bapp1 ;  j>=128 -> Q = h @ Wapp1[256:]
__global__ __launch_bounds__(256)
void k2_pq(const float* __restrict__ h, const float* __restrict__ W1,
           const float* __restrict__ b1, float* __restrict__ PQ) {
  __shared__ float As[32][33], Bs[32][33];
  const int tx = threadIdx.x & 31, ty = threadIdx.x >> 5;
  const int bm = blockIdx.y * 32, bn = blockIdx.x * 32;
  const float* B = W1 + (bn >= 128 ? 256 * 128 : 0);
  const int bc0 = bn & 127;
  float acc[4] = {0.f, 0.f, 0.f, 0.f};
  for (int k0 = 0; k0 < 256; k0 += 32) {
#pragma unroll
    for (int i = 0; i < 4; ++i) {
      int idx = (int)threadIdx.x + i * 256, r = idx >> 5, c = idx & 31;
      As[r][c] = h[(bm + r) * 256 + k0 + c];
      Bs[r][c] = B[(k0 + r) * 128 + bc0 + c];
    }
    __syncthreads();
#pragma unroll
    for (int kk = 0; kk < 32; ++kk) {
      float bv = Bs[kk][tx];
#pragma unroll
      for (int i = 0; i < 4; ++i) acc[i] = fmaf(As[ty + 8 * i][kk], bv, acc[i]);
    }
    __syncthreads();
  }
  float bias = (bn < 128) ? b1[bn + tx] : 0.f;
#pragma unroll
  for (int i = 0; i < 4; ++i)
    PQ[(bm + ty + 8 * i) * 256 + bn + tx] = acc[i] + bias;
}

// ---------------------------------------------------------------------------
// K3: per-edge app/geo/e. blocks 0..255 = half0 (s fixed), 256..511 = half1.
__global__ __launch_bounds__(256)
void k3_edges(const float* __restrict__ PQ, const float* __restrict__ coords,
              const float* __restrict__ co, const float* __restrict__ Wapp2,
              const float* __restrict__ bapp2, const float* __restrict__ Wg1,
              const float* __restrict__ bg1, const float* __restrict__ Wg2,
              const float* __restrict__ bg2, const float* __restrict__ Wa1,
              const float* __restrict__ ba1, const float* __restrict__ Wa2,
              const float* __restrict__ ba2, float* __restrict__ E1,
              float* __restrict__ E2, float* __restrict__ iou1) {
  __shared__ float sFix[128], sW2[128], sWg1[256], sGfix[32], sWg2[32];
  __shared__ float sWa1[16], sBa1[8], sWa2[8];
  const int tid = threadIdx.x;
  const int half = blockIdx.x >> 8;
  const int fr = blockIdx.x & 255;
  if (tid < 128) {
    sFix[tid] = PQ[fr * 256 + (half ? 128 + tid : tid)];
    sW2[tid] = Wapp2[tid];
  }
  sWg1[tid] = Wg1[tid & 255];
  if (tid < 32) sWg2[tid] = Wg2[tid];
  if (tid < 16) sWa1[tid] = Wa1[tid];
  if (tid < 8) { sBa1[tid] = ba1[tid]; sWa2[tid] = Wa2[tid]; }
  __syncthreads();
  if (tid < 32) {
    const int offf = half ? 4 : 0;
    float g = bg1[tid];
#pragma unroll
    for (int q = 0; q < 4; ++q) g = fmaf(coords[fr * 4 + q], sWg1[(offf + q) * 32 + tid], g);
    sGfix[tid] = g;
  }
  __syncthreads();

  const int d = tid;
  const int pnode = 256 + d;
  const float* tb = PQ + pnode * 256 + (half ? 0 : 128);
  float z = 0.f;
#pragma unroll
  for (int j = 0; j < 128; j += 4) {
    float4 q4 = *reinterpret_cast<const float4*>(tb + j);
    float a;
    a = sFix[j + 0] + q4.x; a = a > 0.f ? a : 0.f; z = fmaf(a, sW2[j + 0], z);
    a = sFix[j + 1] + q4.y; a = a > 0.f ? a : 0.f; z = fmaf(a, sW2[j + 1], z);
    a = sFix[j + 2] + q4.z; a = a > 0.f ? a : 0.f; z = fmaf(a, sW2[j + 2], z);
    a = sFix[j + 3] + q4.w; a = a > 0.f ? a : 0.f; z = fmaf(a, sW2[j + 3], z);
  }
  const float app = sigmoidf_(z + bapp2[0]);
  float4 cp = *reinterpret_cast<const float4*>(coords + pnode * 4);
  const int offp = half ? 0 : 4;
  float gz = 0.f;
#pragma unroll
  for (int m = 0; m < 32; ++m) {
    float hm = sGfix[m];
    hm = fmaf(cp.x, sWg1[(offp + 0) * 32 + m], hm);
    hm = fmaf(cp.y, sWg1[(offp + 1) * 32 + m], hm);
    hm = fmaf(cp.z, sWg1[(offp + 2) * 32 + m], hm);
    hm = fmaf(cp.w, sWg1[(offp + 3) * 32 + m], hm);
    hm = hm > 0.f ? hm : 0.f;
    gz = fmaf(hm, sWg2[m], gz);
  }
  const float geo = sigmoidf_(gz + bg2[0]);
  float ez = 0.f;
#pragma unroll
  for (int m = 0; m < 8; ++m) {
    float hm = fmaf(app, sWa1[m], fmaf(geo, sWa1[8 + m], sBa1[m]));
    hm = hm > 0.f ? hm : 0.f;
    ez = fmaf(hm, sWa2[m], ez);
  }
  const float e = sigmoidf_(ez + ba2[0]);
  if (half == 0) {
    E1[fr * 256 + d] = e;
    float4 A4 = *reinterpret_cast<const float4*>(co + fr * 4);
    float4 B4 = *reinterpret_cast<const float4*>(co + pnode * 4);
    float ix1 = fmaxf(A4.x, B4.x), iy1 = fmaxf(A4.y, B4.y);
    float ix2 = fminf(A4.z, B4.z), iy2 = fminf(A4.w, B4.w);
    float inter = fmaxf(ix2 - ix1, 0.f) * fmaxf(iy2 - iy1, 0.f);
    float areaA = (A4.z - A4.x) * (A4.w - A4.y);
    float areaB = (B4.z - B4.x) * (B4.w - B4.y);
    iou1[fr * 256 + d] = inter / (areaA + areaB - inter + 1e-8f);
  } else {
    E2[fr * 256 + d] = e;
  }
}

// ---------------------------------------------------------------------------
// K4: agg. z=0: agg[0:256] = E2 @ H_det ; z=1: agg[256:512] = E1^T @ H_track
__global__ __launch_bounds__(256)
void k4_agg(const float* __restrict__ E1, const float* __restrict__ E2,
            const float* __restrict__ h, float* __restrict__ agg) {
  __shared__ float As[32][33], Bs[32][33];
  const int tx = threadIdx.x & 31, ty = threadIdx.x >> 5;
  const int bm = blockIdx.y * 32, bn = blockIdx.x * 32;
  const int zt = blockIdx.z;
  float acc[4] = {0.f, 0.f, 0.f, 0.f};
  for (int k0 = 0; k0 < 256; k0 += 32) {
#pragma unroll
    for (int i = 0; i < 4; ++i) {
      int idx = (int)threadIdx.x + i * 256, r = idx >> 5, c = idx & 31;
      if (zt == 0) {
        As[r][c] = E2[(bm + r) * 256 + k0 + c];
        Bs[r][c] = h[(256 + k0 + r) * 256 + bn + c];
      } else {
        As[r][c] = E1[(k0 + r) * 256 + bm + c];
        Bs[r][c] = h[(k0 + r) * 256 + bn + c];
      }
    }
    __syncthreads();
    if (zt == 0) {
#pragma unroll
      for (int kk = 0; kk < 32; ++kk) {
        float bv = Bs[kk][tx];
#pragma unroll
        for (int i = 0; i < 4; ++i) acc[i] = fmaf(As[ty + 8 * i][kk], bv, acc[i]);
      }
    } else {
#pragma unroll
      for (int kk = 0; kk < 32; ++kk) {
        float bv = Bs[kk][tx];
#pragma unroll
        for (int i = 0; i < 4; ++i) acc[i] = fmaf(As[kk][ty + 8 * i], bv, acc[i]);
      }
    }
    __syncthreads();
  }
  float* C = agg + zt * 65536;
#pragma unroll
  for (int i = 0; i < 4; ++i) C[(bm + ty + 8 * i) * 256 + bn + tx] = acc[i];
}

// ---------------------------------------------------------------------------
// K5: out = relu(h @ Wo1 + agg @ Wo2 + bo)
__global__ __launch_bounds__(256)
void k5_out(const float* __restrict__ h, const float* __restrict__ agg,
            const float* __restrict__ Wo1, const float* __restrict__ Wo2,
            const float* __restrict__ bo, float* __restrict__ outm) {
  __shared__ float As[32][33], Bs[32][33];
  const int tx = threadIdx.x & 31, ty = threadIdx.x >> 5;
  const int bm = blockIdx.y * 32, bn = blockIdx.x * 32;
  float acc[4] = {0.f, 0.f, 0.f, 0.f};
  for (int k0 = 0; k0 < 512; k0 += 32) {
    const float* A = (k0 < 256) ? h : agg;
    const float* B = (k0 < 256) ? Wo1 : Wo2;
    const int ka = k0 & 255;
#pragma unroll
    for (int i = 0; i < 4; ++i) {
      int idx = (int)threadIdx.x + i * 256, r = idx >> 5, c = idx & 31;
      As[r][c] = A[(bm + r) * 256 + ka + c];
      Bs[r][c] = B[(ka + r) * 256 + bn + c];
    }
    __syncthreads();
#pragma unroll
    for (int kk = 0; kk < 32; ++kk) {
      float bv = Bs[kk][tx];
#pragma unroll
      for (int i = 0; i < 4; ++i) acc[i] = fmaf(As[ty + 8 * i][kk], bv, acc[i]);
    }
    __syncthreads();
  }
  float bias = bo[bn + tx];
#pragma unroll
  for (int i = 0; i < 4; ++i) {
    float vv = acc[i] + bias;
    outm[(bm + ty + 8 * i) * 256 + bn + tx] = vv > 0.f ? vv : 0.f;
  }
}

// ---------------------------------------------------------------------------
// K5b: row norms n[i] = max(||out[i]||, 1e-6). one wave per row.
__global__ __launch_bounds__(256)
void k5b_norm(const float* __restrict__ outm, float* __restrict__ nrm) {
  const int lane = threadIdx.x & 63;
  const int row = blockIdx.x * 4 + (threadIdx.x >> 6);
  float4 v4 = *reinterpret_cast<const float4*>(outm + row * 256 + lane * 4);
  float s = v4.x * v4.x + v4.y * v4.y + v4.z * v4.z + v4.w * v4.w;
#pragma unroll
  for (int m = 32; m; m >>= 1) s += __shfl_xor(s, m, 64);
  if (lane == 0) nrm[row] = fmaxf(sqrtf(s), 1e-6f);
}

// ---------------------------------------------------------------------------
// K6: cos + final score MLP -> Mblk[256][256] = exp(5*score). (slack row/col
// of the Sinkhorn matrix is a compile-time constant, handled in k7.)
__global__ __launch_bounds__(256)
void k6_score(const float* __restrict__ outm, const float* __restrict__ nrm,
              const float* __restrict__ iou1, const float* __restrict__ Wf1,
              const float* __restrict__ bf1, const float* __restrict__ Wf2,
              const float* __restrict__ bf2, float* __restrict__ Mblk) {
  const int tid = threadIdx.x;
  const int s = blockIdx.x;
  __shared__ float so[256];
  so[tid] = outm[s * 256 + tid];
  __syncthreads();
  const float* od = outm + (256 + tid) * 256;
  float dot = 0.f;
#pragma unroll 8
  for (int j = 0; j < 256; j += 4) {
    float4 o4 = *reinterpret_cast<const float4*>(od + j);
    dot = fmaf(so[j + 0], o4.x, dot);
    dot = fmaf(so[j + 1], o4.y, dot);
    dot = fmaf(so[j + 2], o4.z, dot);
    dot = fmaf(so[j + 3], o4.w, dot);
  }
  const float cosv = dot / (nrm[s] * nrm[256 + tid]);
  const float i1 = iou1[s * 256 + tid];
  float sz = 0.f;
#pragma unroll
  for (int m = 0; m < 8; ++m) {
    float hm = fmaf(cosv, Wf1[m], fmaf(i1, Wf1[8 + m], bf1[m]));
    hm = hm > 0.f ? hm : 0.f;
    sz = fmaf(hm, Wf2[m], sz);
  }
  const float score = sigmoidf_(sz + bf2[0]);
  Mblk[s * 256 + tid] = expf(5.0f * score);
}

// ---------------------------------------------------------------------------
// K7: Sinkhorn, single 1024-thread block. All of M in LDS as fp16
// (rows padded to 130 half2 = 260 cols to break bank alignment).
// Row pass: 4 lanes per row -> only 2 shuffles per wave (was 96).
// Col pass: 4 cols per lane, packed-half b64 reads, su broadcast.
// Final product uses exact fp32 M from L2 (fp16 used only inside iteration;
// M in [1,e^5], fp16 rel err ~5e-4 -> output abs err ~4e-6 << 7.8e-5 thr).
__global__ __launch_bounds__(1024)
void k7_sink(const float* __restrict__ Mg, float* __restrict__ outp) {
  __shared__ __align__(16) __half2 Msh2[256 * 130];       // 133120 B
  __shared__ __align__(16) float su[264], sv[264];
  __shared__ __align__(16) float psum[16][256];           // 16 KiB
  const int tid = threadIdx.x;
  const int w = tid >> 6, lane = tid & 63;
  const float slack = expf(1.0f);  // exp(LAM*SLACK) = exp(5*0.2)

  // -------- stage M -> LDS fp16
#pragma unroll
  for (int k = 0; k < 16; ++k) {
    const int i = (tid + k * 1024) * 4;           // flat fp32 index
    const float4 f = *reinterpret_cast<const float4*>(&Mg[i]);
    const int r = i >> 8, ch2 = (i & 255) >> 1;   // row, half2-col
    Msh2[r * 130 + ch2] = __floats2half2_rn(f.x, f.y);
    Msh2[r * 130 + ch2 + 1] = __floats2half2_rn(f.z, f.w);
  }
  if (tid < 257) sv[tid] = 1.0f;
  __syncthreads();

  const int q = lane & 3, g4 = lane >> 2;  // row pass: 4 lanes/row, 16 rows/wave
  const float4* sv4 = reinterpret_cast<const float4*>(sv);

  for (int it = 0; it < 8; ++it) {
    // ---- row pass: su[r] = 1/(sum_c M[r][c]*sv[c] + slack*sv[256])
    const float sv256 = sv[256];
    {
      const int row = (w << 4) + g4;
      const __half2* mrow = Msh2 + row * 130 + q * 32;
      float s = 0.f;
#pragma unroll
      for (int k = 0; k < 16; ++k) {
        const uint2 mm = *reinterpret_cast<const uint2*>(mrow + 2 * k);
        const float2 lo = __half22float2(__builtin_bit_cast(__half2, mm.x));
        const float2 hi = __half22float2(__builtin_bit_cast(__half2, mm.y));
        const float4 vv = sv4[q * 16 + k];
        s += lo.x * vv.x + lo.y * vv.y + hi.x * vv.z + hi.y * vv.w;
      }
      s += __shfl_xor(s, 1, 64);
      s += __shfl_xor(s, 2, 64);
      if (q == 0) su[row] = 1.0f / (s + slack * sv256);
    }
    if (w == 0) {  // slack row: su[256] = 1/(slack * sum(sv[0..256]))
      float s = sv[lane] + sv[lane + 64] + sv[lane + 128] + sv[lane + 192] +
                (lane == 0 ? sv256 : 0.f);
#pragma unroll
      for (int m = 32; m; m >>= 1) s += __shfl_xor(s, m, 64);
      if (lane == 0) su[256] = 1.0f / (slack * s);
    }
    __syncthreads();
    // ---- col pass: psum[w][c] partial over rows w*16..w*16+15; 4 cols/lane
    {
      float a0 = 0.f, a1 = 0.f, a2 = 0.f, a3 = 0.f;
#pragma unroll
      for (int rr = 0; rr < 16; ++rr) {
        const int r = (w << 4) + rr;
        const float ur = su[r];
        const uint2 mm = *reinterpret_cast<const uint2*>(Msh2 + r * 130 + lane * 2);
        const float2 lo = __half22float2(__builtin_bit_cast(__half2, mm.x));
        const float2 hi = __half22float2(__builtin_bit_cast(__half2, mm.y));
        a0 = fmaf(lo.x, ur, a0);
        a1 = fmaf(lo.y, ur, a1);
        a2 = fmaf(hi.x, ur, a2);
        a3 = fmaf(hi.y, ur, a3);
      }
      float4 o; o.x = a0; o.y = a1; o.z = a2; o.w = a3;
      *reinterpret_cast<float4*>(&psum[w][lane * 4]) = o;
    }
    if (w == 4) {  // slack col: sv[256] = 1/(slack * sum(su[0..256]))
      float s = su[lane] + su[lane + 64] + su[lane + 128] + su[lane + 192] +
                (lane == 0 ? su[256] : 0.f);
#pragma unroll
      for (int m = 32; m; m >>= 1) s += __shfl_xor(s, m, 64);
      if (lane == 0) sv[256] = 1.0f / (slack * s);
    }
    __syncthreads();
    if (tid < 256) {
      float s = 0.f;
#pragma unroll
      for (int g = 0; g < 16; ++g) s += psum[g][tid];
      sv[tid] = 1.0f / (s + slack * su[256]);
    }
    __syncthreads();
  }
  // -------- output: out[r][c] = su[r] * M[r][c] * sv[c]  (exact fp32 M)
#pragma unroll
  for (int k = 0; k < 16; ++k) {
    const int b = (tid + k * 1024) * 4;
    const int r = b >> 8, c = b & 255;
    const float4 m4 = *reinterpret_cast<const float4*>(&Mg[b]);
    const float4 vv = *reinterpret_cast<const float4*>(&sv[c]);
    const float ur = su[r];
    float4 o;
    o.x = ur * m4.x * vv.x;
    o.y = ur * m4.y * vv.y;
    o.z = ur * m4.z * vv.z;
    o.w = ur * m4.w * vv.w;
    *reinterpret_cast<float4*>(&outp[b]) = o;
  }
}

// ---------------------------------------------------------------------------
extern "C" void kernel_launch(void* const* d_in, const int* in_sizes, int n_in,
                              void* d_out, int out_size, void* d_ws, size_t ws_size,
                              hipStream_t stream) {
  (void)in_sizes; (void)n_in; (void)out_size; (void)ws_size;
  const float* x      = (const float*)d_in[0];
  const float* coords = (const float*)d_in[1];
  const float* co     = (const float*)d_in[2];
  // d_in[3] = edge_index (int32) — structure is deterministic, not needed
  const float* Wc    = (const float*)d_in[4];
  const float* bc    = (const float*)d_in[5];
  const float* Wapp1 = (const float*)d_in[6];
  const float* bapp1 = (const float*)d_in[7];
  const float* Wapp2 = (const float*)d_in[8];
  const float* bapp2 = (const float*)d_in[9];
  const float* Wg1   = (const float*)d_in[10];
  const float* bg1   = (const float*)d_in[11];
  const float* Wg2   = (const float*)d_in[12];
  const float* bg2   = (const float*)d_in[13];
  const float* Wa1   = (const float*)d_in[14];
  const float* ba1   = (const float*)d_in[15];
  const float* Wa2   = (const float*)d_in[16];
  const float* ba2   = (const float*)d_in[17];
  const float* Wo1   = (const float*)d_in[18];
  const float* Wo2   = (const float*)d_in[19];
  const float* bo    = (const float*)d_in[20];
  const float* Wf1   = (const float*)d_in[21];
  const float* bf1   = (const float*)d_in[22];
  const float* Wf2   = (const float*)d_in[23];
  const float* bf2   = (const float*)d_in[24];

  float* ws   = (float*)d_ws;
  float* h    = ws + 0;        // 512*256
  float* PQ   = ws + 131072;   // 512*256
  float* E1   = ws + 262144;   // 256*256
  float* E2   = ws + 327680;   // 256*256
  float* iou1 = ws + 393216;   // 256*256
  float* agg  = ws + 458752;   // 512*256
  float* outm = ws + 589824;   // 512*256
  float* nrm  = ws + 720896;   // 512
  float* Mblk = ws + 721408;   // 256*256

  k1_h<<<dim3(8, 16), 256, 0, stream>>>(x, Wc, bc, h);
  k2_pq<<<dim3(8, 16), 256, 0, stream>>>(h, Wapp1, bapp1, PQ);
  k3_edges<<<512, 256, 0, stream>>>(PQ, coords, co, Wapp2, bapp2, Wg1, bg1, Wg2,
                                    bg2, Wa1, ba1, Wa2, ba2, E1, E2, iou1);
  k4_agg<<<dim3(8, 8, 2), 256, 0, stream>>>(E1, E2, h, agg);
  k5_out<<<dim3(8, 16), 256, 0, stream>>>(h, agg, Wo1, Wo2, bo, outm);
  k5b_norm<<<128, 256, 0, stream>>>(outm, nrm);
  k6_score<<<256, 256, 0, stream>>>(outm, nrm, iou1, Wf1, bf1, Wf2, bf2, Mblk);
  k7_sink<<<1, 1024, 0, stream>>>(Mblk, (float*)d_out);
}

// Round 4
// 139.942 us; speedup vs baseline: 1.6563x; 1.1495x over previous
//
#include <hip/hip_runtime.h>
#include <math.h>

// completeNet: graph-net + Sinkhorn, fully factorized.
// T=256 tracks (nodes 0..255), M=256 dets (nodes 256..511), D_IN=512, D_EMB=256.

__device__ __forceinline__ float sigmoidf_(float x) { return 1.0f / (1.0f + expf(-x)); }

typedef _Float16 h2t __attribute__((ext_vector_type(2)));

__device__ __forceinline__ h2t pack2(float x, float y) {
  h2t r; r.x = (_Float16)x; r.y = (_Float16)y; return r;
}
__device__ __forceinline__ float fdot2f(h2t a, h2t b, float c) {
  return __builtin_amdgcn_fdot2(a, b, c, false);
}
template <int CTRL>
__device__ __forceinline__ float dpp_get(float x) {  // partner value via DPP perm
  return __builtin_bit_cast(
      float, __builtin_amdgcn_mov_dpp(__builtin_bit_cast(int, x), CTRL, 0xF, 0xF, false));
}
template <int IMM>
__device__ __forceinline__ float swz_get(float x) {  // ds_swizzle xor pattern
  return __builtin_bit_cast(
      float, __builtin_amdgcn_ds_swizzle(__builtin_bit_cast(int, x), IMM));
}
// sum over the 16-lane DPP row (xor1, xor2, xor7, xor15 — all VALU)
__device__ __forceinline__ float allred16(float x) {
  x += dpp_get<0xB1>(x);   // quad_perm [1,0,3,2] = xor1
  x += dpp_get<0x4E>(x);   // quad_perm [2,3,0,1] = xor2
  x += dpp_get<0x141>(x);  // row_half_mirror = xor7
  x += dpp_get<0x140>(x);  // row_mirror = xor15
  return x;
}

// ---------------------------------------------------------------------------
// K1: h = relu(x @ W_cnn + b_cnn)   (512x512)@(512x256)
__global__ __launch_bounds__(256)
void k1_h(const float* __restrict__ x, const float* __restrict__ Wc,
          const float* __restrict__ bc, float* __restrict__ h) {
  __shared__ float As[32][33], Bs[32][33];
  const int tx = threadIdx.x & 31, ty = threadIdx.x >> 5;
  const int bm = blockIdx.y * 32, bn = blockIdx.x * 32;
  float acc[4] = {0.f, 0.f, 0.f, 0.f};
  for (int k0 = 0; k0 < 512; k0 += 32) {
#pragma unroll
    for (int i = 0; i < 4; ++i) {
      int idx = (int)threadIdx.x + i * 256, r = idx >> 5, c = idx & 31;
      As[r][c] = x[(bm + r) * 512 + k0 + c];
      Bs[r][c] = Wc[(k0 + r) * 256 + bn + c];
    }
    __syncthreads();
#pragma unroll
    for (int kk = 0; kk < 32; ++kk) {
      float bv = Bs[kk][tx];
#pragma unroll
      for (int i = 0; i < 4; ++i) acc[i] = fmaf(As[ty + 8 * i][kk], bv, acc[i]);
    }
    __syncthreads();
  }
  float bias = bc[bn + tx];
#pragma unroll
  for (int i = 0; i < 4; ++i) {
    float vv = acc[i] + bias;
    h[(bm + ty + 8 * i) * 256 + bn + tx] = vv > 0.f ? vv : 0.f;
  }
}

// ---------------------------------------------------------------------------
// K2: PQ[:, :128] = h @ Wapp1[:256] + bapp1 ; PQ[:, 128:] = h @ Wapp1[256:]
__global__ __launch_bounds__(256)
void k2_pq(const float* __restrict__ h, const float* __restrict__ W1,
           const float* __restrict__ b1, float* __restrict__ PQ) {
  __shared__ float As[32][33], Bs[32][33];
  const int tx = threadIdx.x & 31, ty = threadIdx.x >> 5;
  const int bm = blockIdx.y * 32, bn = blockIdx.x * 32;
  const float* B = W1 + (bn >= 128 ? 256 * 128 : 0);
  const int bc0 = bn & 127;
  float acc[4] = {0.f, 0.f, 0.f, 0.f};
  for (int k0 = 0; k0 < 256; k0 += 32) {
#pragma unroll
    for (int i = 0; i < 4; ++i) {
      int idx = (int)threadIdx.x + i * 256, r = idx >> 5, c = idx & 31;
      As[r][c] = h[(bm + r) * 256 + k0 + c];
      Bs[r][c] = B[(k0 + r) * 128 + bc0 + c];
    }
    __syncthreads();
#pragma unroll
    for (int kk = 0; kk < 32; ++kk) {
      float bv = Bs[kk][tx];
#pragma unroll
      for (int i = 0; i < 4; ++i) acc[i] = fmaf(As[ty + 8 * i][kk], bv, acc[i]);
    }
    __syncthreads();
  }
  float bias = (bn < 128) ? b1[bn + tx] : 0.f;
#pragma unroll
  for (int i = 0; i < 4; ++i)
    PQ[(bm + ty + 8 * i) * 256 + bn + tx] = acc[i] + bias;
}

// ---------------------------------------------------------------------------
// K3: per-edge app/geo/e. blocks 0..255 = half0 (s fixed), 256..511 = half1.
__global__ __launch_bounds__(256)
void k3_edges(const float* __restrict__ PQ, const float* __restrict__ coords,
              const float* __restrict__ co, const float* __restrict__ Wapp2,
              const float* __restrict__ bapp2, const float* __restrict__ Wg1,
              const float* __restrict__ bg1, const float* __restrict__ Wg2,
              const float* __restrict__ bg2, const float* __restrict__ Wa1,
              const float* __restrict__ ba1, const float* __restrict__ Wa2,
              const float* __restrict__ ba2, float* __restrict__ E1,
              float* __restrict__ E2, float* __restrict__ iou1) {
  __shared__ float sFix[128], sW2[128], sWg1[256], sGfix[32], sWg2[32];
  __shared__ float sWa1[16], sBa1[8], sWa2[8];
  const int tid = threadIdx.x;
  const int half = blockIdx.x >> 8;
  const int fr = blockIdx.x & 255;
  if (tid < 128) {
    sFix[tid] = PQ[fr * 256 + (half ? 128 + tid : tid)];
    sW2[tid] = Wapp2[tid];
  }
  sWg1[tid] = Wg1[tid & 255];
  if (tid < 32) sWg2[tid] = Wg2[tid];
  if (tid < 16) sWa1[tid] = Wa1[tid];
  if (tid < 8) { sBa1[tid] = ba1[tid]; sWa2[tid] = Wa2[tid]; }
  __syncthreads();
  if (tid < 32) {
    const int offf = half ? 4 : 0;
    float g = bg1[tid];
#pragma unroll
    for (int q = 0; q < 4; ++q) g = fmaf(coords[fr * 4 + q], sWg1[(offf + q) * 32 + tid], g);
    sGfix[tid] = g;
  }
  __syncthreads();

  const int d = tid;
  const int pnode = 256 + d;
  const float* tb = PQ + pnode * 256 + (half ? 0 : 128);
  float z = 0.f;
#pragma unroll
  for (int j = 0; j < 128; j += 4) {
    float4 q4 = *reinterpret_cast<const float4*>(tb + j);
    float a;
    a = sFix[j + 0] + q4.x; a = a > 0.f ? a : 0.f; z = fmaf(a, sW2[j + 0], z);
    a = sFix[j + 1] + q4.y; a = a > 0.f ? a : 0.f; z = fmaf(a, sW2[j + 1], z);
    a = sFix[j + 2] + q4.z; a = a > 0.f ? a : 0.f; z = fmaf(a, sW2[j + 2], z);
    a = sFix[j + 3] + q4.w; a = a > 0.f ? a : 0.f; z = fmaf(a, sW2[j + 3], z);
  }
  const float app = sigmoidf_(z + bapp2[0]);
  float4 cp = *reinterpret_cast<const float4*>(coords + pnode * 4);
  const int offp = half ? 0 : 4;
  float gz = 0.f;
#pragma unroll
  for (int m = 0; m < 32; ++m) {
    float hm = sGfix[m];
    hm = fmaf(cp.x, sWg1[(offp + 0) * 32 + m], hm);
    hm = fmaf(cp.y, sWg1[(offp + 1) * 32 + m], hm);
    hm = fmaf(cp.z, sWg1[(offp + 2) * 32 + m], hm);
    hm = fmaf(cp.w, sWg1[(offp + 3) * 32 + m], hm);
    hm = hm > 0.f ? hm : 0.f;
    gz = fmaf(hm, sWg2[m], gz);
  }
  const float geo = sigmoidf_(gz + bg2[0]);
  float ez = 0.f;
#pragma unroll
  for (int m = 0; m < 8; ++m) {
    float hm = fmaf(app, sWa1[m], fmaf(geo, sWa1[8 + m], sBa1[m]));
    hm = hm > 0.f ? hm : 0.f;
    ez = fmaf(hm, sWa2[m], ez);
  }
  const float e = sigmoidf_(ez + ba2[0]);
  if (half == 0) {
    E1[fr * 256 + d] = e;
    float4 A4 = *reinterpret_cast<const float4*>(co + fr * 4);
    float4 B4 = *reinterpret_cast<const float4*>(co + pnode * 4);
    float ix1 = fmaxf(A4.x, B4.x), iy1 = fmaxf(A4.y, B4.y);
    float ix2 = fminf(A4.z, B4.z), iy2 = fminf(A4.w, B4.w);
    float inter = fmaxf(ix2 - ix1, 0.f) * fmaxf(iy2 - iy1, 0.f);
    float areaA = (A4.z - A4.x) * (A4.w - A4.y);
    float areaB = (B4.z - B4.x) * (B4.w - B4.y);
    iou1[fr * 256 + d] = inter / (areaA + areaB - inter + 1e-8f);
  } else {
    E2[fr * 256 + d] = e;
  }
}

// ---------------------------------------------------------------------------
// K4: agg. z=0: agg[0:256] = E2 @ H_det ; z=1: agg[256:512] = E1^T @ H_track
__global__ __launch_bounds__(256)
void k4_agg(const float* __restrict__ E1, const float* __restrict__ E2,
            const float* __restrict__ h, float* __restrict__ agg) {
  __shared__ float As[32][33], Bs[32][33];
  const int tx = threadIdx.x & 31, ty = threadIdx.x >> 5;
  const int bm = blockIdx.y * 32, bn = blockIdx.x * 32;
  const int zt = blockIdx.z;
  float acc[4] = {0.f, 0.f, 0.f, 0.f};
  for (int k0 = 0; k0 < 256; k0 += 32) {
#pragma unroll
    for (int i = 0; i < 4; ++i) {
      int idx = (int)threadIdx.x + i * 256, r = idx >> 5, c = idx & 31;
      if (zt == 0) {
        As[r][c] = E2[(bm + r) * 256 + k0 + c];
        Bs[r][c] = h[(256 + k0 + r) * 256 + bn + c];
      } else {
        As[r][c] = E1[(k0 + r) * 256 + bm + c];
        Bs[r][c] = h[(k0 + r) * 256 + bn + c];
      }
    }
    __syncthreads();
    if (zt == 0) {
#pragma unroll
      for (int kk = 0; kk < 32; ++kk) {
        float bv = Bs[kk][tx];
#pragma unroll
        for (int i = 0; i < 4; ++i) acc[i] = fmaf(As[ty + 8 * i][kk], bv, acc[i]);
      }
    } else {
#pragma unroll
      for (int kk = 0; kk < 32; ++kk) {
        float bv = Bs[kk][tx];
#pragma unroll
        for (int i = 0; i < 4; ++i) acc[i] = fmaf(As[kk][ty + 8 * i], bv, acc[i]);
      }
    }
    __syncthreads();
  }
  float* C = agg + zt * 65536;
#pragma unroll
  for (int i = 0; i < 4; ++i) C[(bm + ty + 8 * i) * 256 + bn + tx] = acc[i];
}

// ---------------------------------------------------------------------------
// K5: out = relu(h @ Wo1 + agg @ Wo2 + bo)
__global__ __launch_bounds__(256)
void k5_out(const float* __restrict__ h, const float* __restrict__ agg,
            const float* __restrict__ Wo1, const float* __restrict__ Wo2,
            const float* __restrict__ bo, float* __restrict__ outm) {
  __shared__ float As[32][33], Bs[32][33];
  const int tx = threadIdx.x & 31, ty = threadIdx.x >> 5;
  const int bm = blockIdx.y * 32, bn = blockIdx.x * 32;
  float acc[4] = {0.f, 0.f, 0.f, 0.f};
  for (int k0 = 0; k0 < 512; k0 += 32) {
    const float* A = (k0 < 256) ? h : agg;
    const float* B = (k0 < 256) ? Wo1 : Wo2;
    const int ka = k0 & 255;
#pragma unroll
    for (int i = 0; i < 4; ++i) {
      int idx = (int)threadIdx.x + i * 256, r = idx >> 5, c = idx & 31;
      As[r][c] = A[(bm + r) * 256 + ka + c];
      Bs[r][c] = B[(ka + r) * 256 + bn + c];
    }
    __syncthreads();
#pragma unroll
    for (int kk = 0; kk < 32; ++kk) {
      float bv = Bs[kk][tx];
#pragma unroll
      for (int i = 0; i < 4; ++i) acc[i] = fmaf(As[ty + 8 * i][kk], bv, acc[i]);
    }
    __syncthreads();
  }
  float bias = bo[bn + tx];
#pragma unroll
  for (int i = 0; i < 4; ++i) {
    float vv = acc[i] + bias;
    outm[(bm + ty + 8 * i) * 256 + bn + tx] = vv > 0.f ? vv : 0.f;
  }
}

// ---------------------------------------------------------------------------
// K6: cos + norms (fused; was k5b) + final score MLP -> Mblk = exp(5*score).
__global__ __launch_bounds__(256)
void k6_score(const float* __restrict__ outm, const float* __restrict__ iou1,
              const float* __restrict__ Wf1, const float* __restrict__ bf1,
              const float* __restrict__ Wf2, const float* __restrict__ bf2,
              float* __restrict__ Mblk) {
  const int tid = threadIdx.x;
  const int s = blockIdx.x;
  __shared__ float so[256];
  so[tid] = outm[s * 256 + tid];
  __syncthreads();
  const float* od = outm + (256 + tid) * 256;
  float dot = 0.f, na2 = 0.f, nb2 = 0.f;
#pragma unroll 8
  for (int j = 0; j < 256; j += 4) {
    float4 o4 = *reinterpret_cast<const float4*>(od + j);
    float s0 = so[j + 0], s1 = so[j + 1], s2 = so[j + 2], s3 = so[j + 3];
    dot = fmaf(s0, o4.x, dot); dot = fmaf(s1, o4.y, dot);
    dot = fmaf(s2, o4.z, dot); dot = fmaf(s3, o4.w, dot);
    na2 = fmaf(s0, s0, na2); na2 = fmaf(s1, s1, na2);
    na2 = fmaf(s2, s2, na2); na2 = fmaf(s3, s3, na2);
    nb2 = fmaf(o4.x, o4.x, nb2); nb2 = fmaf(o4.y, o4.y, nb2);
    nb2 = fmaf(o4.z, o4.z, nb2); nb2 = fmaf(o4.w, o4.w, nb2);
  }
  const float na = fmaxf(sqrtf(na2), 1e-6f);
  const float nb = fmaxf(sqrtf(nb2), 1e-6f);
  const float cosv = dot / (na * nb);
  const float i1 = iou1[s * 256 + tid];
  float sz = 0.f;
#pragma unroll
  for (int m = 0; m < 8; ++m) {
    float hm = fmaf(cosv, Wf1[m], fmaf(i1, Wf1[8 + m], bf1[m]));
    hm = hm > 0.f ? hm : 0.f;
    sz = fmaf(hm, Wf2[m], sz);
  }
  const float score = sigmoidf_(sz + bf2[0]);
  Mblk[s * 256 + tid] = expf(5.0f * score);
}

// ---------------------------------------------------------------------------
// K7: Sinkhorn, single 1024-thread block, M register-resident (fp16, twice).
// Row layout: wave w owns rows w*16..+15; lane owns cols 4l..4l+3.
// Col layout: wave w owns cols w*16..+15; lane owns rows {16k + (l>>2)}.
// Dots via v_dot2_f32_f16 (fp32 accum); folds via DPP (VALU) + 2 swizzles.
// sv carried as 256*sv in fp16 (avoids subnormals); scalars su256/sv256 in regs.
__global__ __launch_bounds__(1024)
void k7_sink(const float* __restrict__ Mg, float* __restrict__ outp) {
  __shared__ float su_f[256];
  __shared__ float su_t[16 * 20];  // su_t[a*20+k] = su[16k+a]
  __shared__ float sv_f[256];
  __shared__ h2t svh[128];         // 256*sv as half2
  __shared__ float wsumV[16];      // per-wave sum of new sv
  const int tid = threadIdx.x;
  const int w = tid >> 6, l = tid & 63;
  const float slack = 2.71828182845904523536f;  // exp(LAM*SLACK) = exp(1)
  const int rev = ((l & 1) << 3) | ((l & 2) << 1) | ((l & 4) >> 1) | ((l & 8) >> 3);

  // ---- stage M into registers (fp16), row copy + col copy
  h2t mrA[16], mrB[16];
#pragma unroll
  for (int i = 0; i < 16; ++i) {
    const float4 f = *reinterpret_cast<const float4*>(Mg + (w * 16 + i) * 256 + 4 * l);
    mrA[i] = pack2(f.x, f.y);
    mrB[i] = pack2(f.z, f.w);
  }
  h2t mc[8][4];  // mc[a][j] = half2(M[32a + r'][c0+j], M[32a+16+r'][c0+j])
#pragma unroll
  for (int a = 0; a < 8; ++a) {
    const float4 f0 = *reinterpret_cast<const float4*>(
        Mg + (32 * a + (l >> 2)) * 256 + w * 16 + (l & 3) * 4);
    const float4 f1 = *reinterpret_cast<const float4*>(
        Mg + (32 * a + 16 + (l >> 2)) * 256 + w * 16 + (l & 3) * 4);
    mc[a][0] = pack2(f0.x, f1.x);
    mc[a][1] = pack2(f0.y, f1.y);
    mc[a][2] = pack2(f0.z, f1.z);
    mc[a][3] = pack2(f0.w, f1.w);
  }
  if (tid < 128) svh[tid] = pack2(256.0f, 256.0f);
  __syncthreads();

  float sv256 = 1.0f;
  const bool b0 = l & 1, b1 = l & 2, b2 = l & 4, b3 = l & 8;
  for (int it = 0; it < 8; ++it) {
    // ---- sv_tot (previous generation) -> su256 (slack row)
    float sv_tot;
    if (it == 0) sv_tot = 257.0f;
    else sv_tot = allred16(wsumV[l & 15]) + sv256;
    const float su256 = 1.0f / (slack * sv_tot);
    // ---- row pass: p[i] = 256 * sum_c M[w*16+i][c] * sv[c] over own 4 cols
    const h2t sva = svh[2 * l], svb = svh[2 * l + 1];
    float p[16];
#pragma unroll
    for (int i = 0; i < 16; ++i) p[i] = fdot2f(mrA[i], sva, fdot2f(mrB[i], svb, 0.0f));
    // halving fold: reg-bit3..0 <- lane-bit0..3 (exchanges xor1,2,7,15 via DPP)
#pragma unroll
    for (int i = 0; i < 8; ++i) {
      const float keep = b0 ? p[i + 8] : p[i], give = b0 ? p[i] : p[i + 8];
      p[i] = keep + dpp_get<0xB1>(give);
    }
#pragma unroll
    for (int i = 0; i < 4; ++i) {
      const float keep = b1 ? p[i + 4] : p[i], give = b1 ? p[i] : p[i + 4];
      p[i] = keep + dpp_get<0x4E>(give);
    }
#pragma unroll
    for (int i = 0; i < 2; ++i) {
      const float keep = b2 ? p[i + 2] : p[i], give = b2 ? p[i] : p[i + 2];
      p[i] = keep + dpp_get<0x141>(give);
    }
    {
      const float keep = b3 ? p[1] : p[0], give = b3 ? p[0] : p[1];
      p[0] = keep + dpp_get<0x140>(give);
    }
    float S = p[0];
    S += swz_get<0x401F>(S);        // xor16
    S += __shfl_xor(S, 32, 64);     // xor32
    const float su_val = 1.0f / (S * 0.00390625f + slack * sv256);
    if (l < 16) {
      su_f[w * 16 + rev] = su_val;
      su_t[rev * 20 + w] = su_val;
    }
    __syncthreads();
    // ---- col pass: lane's 16 rows = {16k + (l>>2)}
    float su16[16];
#pragma unroll
    for (int k = 0; k < 16; k += 4) {
      const float4 t = *reinterpret_cast<const float4*>(&su_t[(l >> 2) * 20 + k]);
      su16[k] = t.x; su16[k + 1] = t.y; su16[k + 2] = t.z; su16[k + 3] = t.w;
    }
    float pc[4] = {0.f, 0.f, 0.f, 0.f};
#pragma unroll
    for (int a = 0; a < 8; ++a) {
      const h2t uh = pack2(256.0f * su16[2 * a], 256.0f * su16[2 * a + 1]);
      pc[0] = fdot2f(mc[a][0], uh, pc[0]);
      pc[1] = fdot2f(mc[a][1], uh, pc[1]);
      pc[2] = fdot2f(mc[a][2], uh, pc[2]);
      pc[3] = fdot2f(mc[a][3], uh, pc[3]);
    }
    // su_tot (for sv256 of next generation)
    float sup = su16[0];
#pragma unroll
    for (int k = 1; k < 16; ++k) sup += su16[k];
    sup += swz_get<0x101F>(sup);    // xor4
    sup += swz_get<0x201F>(sup);    // xor8
    sup += swz_get<0x401F>(sup);    // xor16
    sup += __shfl_xor(sup, 32, 64); // xor32
    const float sv256n = 1.0f / (slack * (sup + su256));
    // fold pc over lane bits 2 (xor4) and 3 (xor8)
#pragma unroll
    for (int i = 0; i < 2; ++i) {
      const float keep = b2 ? pc[i + 2] : pc[i], give = b2 ? pc[i] : pc[i + 2];
      pc[i] = keep + swz_get<0x101F>(give);
    }
    {
      const float keep = b3 ? pc[1] : pc[0], give = b3 ? pc[0] : pc[1];
      pc[0] = keep + swz_get<0x201F>(give);
    }
    float PC = pc[0];
    PC += swz_get<0x401F>(PC);
    PC += __shfl_xor(PC, 32, 64);
    const float sv_val = 1.0f / (PC * 0.00390625f + slack * su256);
    const int colidx = w * 16 + (l & 3) * 4 + ((l >> 2) & 1) * 2 + ((l >> 3) & 1);
    if (l < 16) sv_f[colidx] = sv_val;
    const float partner = __shfl_xor(sv_val * 256.0f, 8, 64);  // pairs differ in bit3
    if (l < 8)
      svh[w * 8 + (l & 3) * 2 + ((l >> 2) & 1)] = pack2(sv_val * 256.0f, partner);
    const float svp = allred16(sv_val);  // sum of wave's 16 new sv
    if (l == 0) wsumV[w] = svp;
    sv256 = sv256n;
    __syncthreads();
  }
  // ---- output: out[r][c] = su[r] * M[r][c] * sv[c]
  const float4 sv4 = *reinterpret_cast<const float4*>(&sv_f[4 * l]);
#pragma unroll
  for (int i = 0; i < 16; ++i) {
    const float uo = su_f[w * 16 + i];
    float4 o;
    o.x = uo * (float)mrA[i].x * sv4.x;
    o.y = uo * (float)mrA[i].y * sv4.y;
    o.z = uo * (float)mrB[i].x * sv4.z;
    o.w = uo * (float)mrB[i].y * sv4.w;
    *reinterpret_cast<float4*>(outp + (w * 16 + i) * 256 + 4 * l) = o;
  }
}

// ---------------------------------------------------------------------------
extern "C" void kernel_launch(void* const* d_in, const int* in_sizes, int n_in,
                              void* d_out, int out_size, void* d_ws, size_t ws_size,
                              hipStream_t stream) {
  (void)in_sizes; (void)n_in; (void)out_size; (void)ws_size;
  const float* x      = (const float*)d_in[0];
  const float* coords = (const float*)d_in[1];
  const float* co     = (const float*)d_in[2];
  // d_in[3] = edge_index (int32) — structure is deterministic, not needed
  const float* Wc    = (const float*)d_in[4];
  const float* bc    = (const float*)d_in[5];
  const float* Wapp1 = (const float*)d_in[6];
  const float* bapp1 = (const float*)d_in[7];
  const float* Wapp2 = (const float*)d_in[8];
  const float* bapp2 = (const float*)d_in[9];
  const float* Wg1   = (const float*)d_in[10];
  const float* bg1   = (const float*)d_in[11];
  const float* Wg2   = (const float*)d_in[12];
  const float* bg2   = (const float*)d_in[13];
  const float* Wa1   = (const float*)d_in[14];
  const float* ba1   = (const float*)d_in[15];
  const float* Wa2   = (const float*)d_in[16];
  const float* ba2   = (const float*)d_in[17];
  const float* Wo1   = (const float*)d_in[18];
  const float* Wo2   = (const float*)d_in[19];
  const float* bo    = (const float*)d_in[20];
  const float* Wf1   = (const float*)d_in[21];
  const float* bf1   = (const float*)d_in[22];
  const float* Wf2   = (const float*)d_in[23];
  const float* bf2   = (const float*)d_in[24];

  float* ws   = (float*)d_ws;
  float* h    = ws + 0;        // 512*256
  float* PQ   = ws + 131072;   // 512*256
  float* E1   = ws + 262144;   // 256*256
  float* E2   = ws + 327680;   // 256*256
  float* iou1 = ws + 393216;   // 256*256
  float* agg  = ws + 458752;   // 512*256
  float* outm = ws + 589824;   // 512*256
  float* Mblk = ws + 720896;   // 256*256

  k1_h<<<dim3(8, 16), 256, 0, stream>>>(x, Wc, bc, h);
  k2_pq<<<dim3(8, 16), 256, 0, stream>>>(h, Wapp1, bapp1, PQ);
  k3_edges<<<512, 256, 0, stream>>>(PQ, coords, co, Wapp2, bapp2, Wg1, bg1, Wg2,
                                    bg2, Wa1, ba1, Wa2, ba2, E1, E2, iou1);
  k4_agg<<<dim3(8, 8, 2), 256, 0, stream>>>(E1, E2, h, agg);
  k5_out<<<dim3(8, 16), 256, 0, stream>>>(h, agg, Wo1, Wo2, bo, outm);
  k6_score<<<256, 256, 0, stream>>>(outm, iou1, Wf1, bf1, Wf2, bf2, Mblk);
  k7_sink<<<1, 1024, 0, stream>>>(Mblk, (float*)d_out);
}

// Round 5
// 105.034 us; speedup vs baseline: 2.2068x; 1.3324x over previous
//
#include <hip/hip_runtime.h>
#include <math.h>

// completeNet: graph-net + Sinkhorn, fully factorized.
// T=256 tracks (nodes 0..255), M=256 dets (nodes 256..511), D_IN=512, D_EMB=256.
// G-refactor: agg@Wo2 == E@(h@Wo2) = E@G, so G is fused into the PQ GEMM and
// the agg GEMM kernel is eliminated.

__device__ __forceinline__ float sigmoidf_(float x) { return 1.0f / (1.0f + expf(-x)); }

typedef _Float16 h2t __attribute__((ext_vector_type(2)));

__device__ __forceinline__ h2t pack2(float x, float y) {
  h2t r; r.x = (_Float16)x; r.y = (_Float16)y; return r;
}
__device__ __forceinline__ float fdot2f(h2t a, h2t b, float c) {
  return __builtin_amdgcn_fdot2(a, b, c, false);
}
template <int CTRL>
__device__ __forceinline__ float dpp_get(float x) {
  return __builtin_bit_cast(
      float, __builtin_amdgcn_mov_dpp(__builtin_bit_cast(int, x), CTRL, 0xF, 0xF, false));
}
template <int IMM>
__device__ __forceinline__ float swz_get(float x) {
  return __builtin_bit_cast(
      float, __builtin_amdgcn_ds_swizzle(__builtin_bit_cast(int, x), IMM));
}
// sum over each 16-lane DPP row (xor1, xor2, xor7, xor15 — all VALU)
__device__ __forceinline__ float allred16(float x) {
  x += dpp_get<0xB1>(x);   // xor1
  x += dpp_get<0x4E>(x);   // xor2
  x += dpp_get<0x141>(x);  // xor7 (row_half_mirror)
  x += dpp_get<0x140>(x);  // xor15 (row_mirror)
  return x;
}

// ---------------------------------------------------------------------------
// K1: h = relu(x @ W_cnn + b_cnn)   (512x512)@(512x256)
// 32x32 tile; A stored transposed (Ast[k][m], stride 36) -> inner loop is
// 1x ds_read_b128 + 1x ds_read_b32 per 4 FMAs (2.5x fewer LDS instrs).
__global__ __launch_bounds__(256)
void k1_h(const float* __restrict__ x, const float* __restrict__ Wc,
          const float* __restrict__ bc, float* __restrict__ h) {
  __shared__ __align__(16) float Ast[32][36];
  __shared__ float Bs[32][33];
  const int tx = threadIdx.x & 31, ty = threadIdx.x >> 5;
  const int bm = blockIdx.y * 32, bn = blockIdx.x * 32;
  float acc[4] = {0.f, 0.f, 0.f, 0.f};
  for (int k0 = 0; k0 < 512; k0 += 32) {
#pragma unroll
    for (int i = 0; i < 4; ++i) {
      int idx = (int)threadIdx.x + i * 256, r = idx >> 5, c = idx & 31;
      Ast[c][r] = x[(bm + r) * 512 + k0 + c];
      Bs[r][c] = Wc[(k0 + r) * 256 + bn + c];
    }
    __syncthreads();
#pragma unroll
    for (int kk = 0; kk < 32; ++kk) {
      const float4 a4 = *reinterpret_cast<const float4*>(&Ast[kk][4 * ty]);
      const float bv = Bs[kk][tx];
      acc[0] = fmaf(a4.x, bv, acc[0]);
      acc[1] = fmaf(a4.y, bv, acc[1]);
      acc[2] = fmaf(a4.z, bv, acc[2]);
      acc[3] = fmaf(a4.w, bv, acc[3]);
    }
    __syncthreads();
  }
  const float bias = bc[bn + tx];
#pragma unroll
  for (int i = 0; i < 4; ++i) {
    const float vv = acc[i] + bias;
    h[(bm + 4 * ty + i) * 256 + bn + tx] = vv > 0.f ? vv : 0.f;
  }
}

// ---------------------------------------------------------------------------
// K2: PQG[i][j]: j<128 -> P = h@Wapp1[:256] + bapp1; 128<=j<256 -> Q = h@Wapp1[256:];
//               j>=256 -> G = h@Wo2.   (512x512 output, stride 512)
__global__ __launch_bounds__(256)
void k2_pqg(const float* __restrict__ h, const float* __restrict__ W1,
            const float* __restrict__ b1, const float* __restrict__ Wo2,
            float* __restrict__ PQG) {
  __shared__ __align__(16) float Ast[32][36];
  __shared__ float Bs[32][33];
  const int tx = threadIdx.x & 31, ty = threadIdx.x >> 5;
  const int bm = blockIdx.y * 32, bn = blockIdx.x * 32;
  float acc[4] = {0.f, 0.f, 0.f, 0.f};
  for (int k0 = 0; k0 < 256; k0 += 32) {
#pragma unroll
    for (int i = 0; i < 4; ++i) {
      int idx = (int)threadIdx.x + i * 256, r = idx >> 5, c = idx & 31;
      Ast[c][r] = h[(bm + r) * 256 + k0 + c];
      float bvv;
      if (bn < 128)       bvv = W1[(k0 + r) * 128 + bn + c];
      else if (bn < 256)  bvv = W1[(256 + k0 + r) * 128 + (bn - 128) + c];
      else                bvv = Wo2[(k0 + r) * 256 + (bn - 256) + c];
      Bs[r][c] = bvv;
    }
    __syncthreads();
#pragma unroll
    for (int kk = 0; kk < 32; ++kk) {
      const float4 a4 = *reinterpret_cast<const float4*>(&Ast[kk][4 * ty]);
      const float bv = Bs[kk][tx];
      acc[0] = fmaf(a4.x, bv, acc[0]);
      acc[1] = fmaf(a4.y, bv, acc[1]);
      acc[2] = fmaf(a4.z, bv, acc[2]);
      acc[3] = fmaf(a4.w, bv, acc[3]);
    }
    __syncthreads();
  }
  const float bias = (bn < 128) ? b1[bn + tx] : 0.f;
#pragma unroll
  for (int i = 0; i < 4; ++i)
    PQG[(bm + 4 * ty + i) * 512 + bn + tx] = acc[i] + bias;
}

// ---------------------------------------------------------------------------
// K3: per-edge app/geo/e. blocks 0..255 = half0 (track fixed), 256..511 = half1.
__global__ __launch_bounds__(256)
void k3_edges(const float* __restrict__ PQG, const float* __restrict__ coords,
              const float* __restrict__ co, const float* __restrict__ Wapp2,
              const float* __restrict__ bapp2, const float* __restrict__ Wg1,
              const float* __restrict__ bg1, const float* __restrict__ Wg2,
              const float* __restrict__ bg2, const float* __restrict__ Wa1,
              const float* __restrict__ ba1, const float* __restrict__ Wa2,
              const float* __restrict__ ba2, float* __restrict__ E1,
              float* __restrict__ E2, float* __restrict__ iou1) {
  __shared__ __align__(16) float sFix[128], sW2[128], sWg1[256], sGfix[32], sWg2[32];
  __shared__ float sWa1[16], sBa1[8], sWa2[8];
  const int tid = threadIdx.x;
  const int half = blockIdx.x >> 8;
  const int fr = blockIdx.x & 255;
  if (tid < 128) {
    sFix[tid] = PQG[fr * 512 + (half ? 128 + tid : tid)];
    sW2[tid] = Wapp2[tid];
  }
  sWg1[tid] = Wg1[tid & 255];
  if (tid < 32) sWg2[tid] = Wg2[tid];
  if (tid < 16) sWa1[tid] = Wa1[tid];
  if (tid < 8) { sBa1[tid] = ba1[tid]; sWa2[tid] = Wa2[tid]; }
  __syncthreads();
  if (tid < 32) {
    const int offf = half ? 4 : 0;
    float g = bg1[tid];
#pragma unroll
    for (int q = 0; q < 4; ++q) g = fmaf(coords[fr * 4 + q], sWg1[(offf + q) * 32 + tid], g);
    sGfix[tid] = g;
  }
  __syncthreads();

  const int d = tid;
  const int pnode = 256 + d;
  const float* tb = PQG + pnode * 512 + (half ? 0 : 128);
  float z = 0.f;
#pragma unroll
  for (int j = 0; j < 128; j += 4) {
    const float4 q4 = *reinterpret_cast<const float4*>(tb + j);
    const float4 pf = *reinterpret_cast<const float4*>(&sFix[j]);
    const float4 w4 = *reinterpret_cast<const float4*>(&sW2[j]);
    float a;
    a = pf.x + q4.x; a = a > 0.f ? a : 0.f; z = fmaf(a, w4.x, z);
    a = pf.y + q4.y; a = a > 0.f ? a : 0.f; z = fmaf(a, w4.y, z);
    a = pf.z + q4.z; a = a > 0.f ? a : 0.f; z = fmaf(a, w4.z, z);
    a = pf.w + q4.w; a = a > 0.f ? a : 0.f; z = fmaf(a, w4.w, z);
  }
  const float app = sigmoidf_(z + bapp2[0]);
  const float4 cp = *reinterpret_cast<const float4*>(coords + pnode * 4);
  const int offp = half ? 0 : 4;
  float gz = 0.f;
#pragma unroll
  for (int mb = 0; mb < 8; ++mb) {
    const float4 g4 = *reinterpret_cast<const float4*>(&sGfix[4 * mb]);
    const float4 w0 = *reinterpret_cast<const float4*>(&sWg1[(offp + 0) * 32 + 4 * mb]);
    const float4 w1 = *reinterpret_cast<const float4*>(&sWg1[(offp + 1) * 32 + 4 * mb]);
    const float4 w2 = *reinterpret_cast<const float4*>(&sWg1[(offp + 2) * 32 + 4 * mb]);
    const float4 w3 = *reinterpret_cast<const float4*>(&sWg1[(offp + 3) * 32 + 4 * mb]);
    const float4 v2 = *reinterpret_cast<const float4*>(&sWg2[4 * mb]);
    float hm;
    hm = g4.x + cp.x * w0.x + cp.y * w1.x + cp.z * w2.x + cp.w * w3.x;
    hm = hm > 0.f ? hm : 0.f; gz = fmaf(hm, v2.x, gz);
    hm = g4.y + cp.x * w0.y + cp.y * w1.y + cp.z * w2.y + cp.w * w3.y;
    hm = hm > 0.f ? hm : 0.f; gz = fmaf(hm, v2.y, gz);
    hm = g4.z + cp.x * w0.z + cp.y * w1.z + cp.z * w2.z + cp.w * w3.z;
    hm = hm > 0.f ? hm : 0.f; gz = fmaf(hm, v2.z, gz);
    hm = g4.w + cp.x * w0.w + cp.y * w1.w + cp.z * w2.w + cp.w * w3.w;
    hm = hm > 0.f ? hm : 0.f; gz = fmaf(hm, v2.w, gz);
  }
  const float geo = sigmoidf_(gz + bg2[0]);
  float ez = 0.f;
#pragma unroll
  for (int m = 0; m < 8; ++m) {
    float hm = fmaf(app, sWa1[m], fmaf(geo, sWa1[8 + m], sBa1[m]));
    hm = hm > 0.f ? hm : 0.f;
    ez = fmaf(hm, sWa2[m], ez);
  }
  const float e = sigmoidf_(ez + ba2[0]);
  if (half == 0) {
    E1[fr * 256 + d] = e;
    const float4 A4 = *reinterpret_cast<const float4*>(co + fr * 4);
    const float4 B4 = *reinterpret_cast<const float4*>(co + pnode * 4);
    const float ix1 = fmaxf(A4.x, B4.x), iy1 = fmaxf(A4.y, B4.y);
    const float ix2 = fminf(A4.z, B4.z), iy2 = fminf(A4.w, B4.w);
    const float inter = fmaxf(ix2 - ix1, 0.f) * fmaxf(iy2 - iy1, 0.f);
    const float areaA = (A4.z - A4.x) * (A4.w - A4.y);
    const float areaB = (B4.z - B4.x) * (B4.w - B4.y);
    iou1[fr * 256 + d] = inter / (areaA + areaB - inter + 1e-8f);
  } else {
    E2[fr * 256 + d] = e;
  }
}

// ---------------------------------------------------------------------------
// K5: out = relu(h @ Wo1 + E@G + bo)
//   track rows (bm<256): E2 @ G_det (G rows 256..511)
//   det rows  (bm>=256): E1^T @ G_track (G rows 0..255)
__global__ __launch_bounds__(256)
void k5_out(const float* __restrict__ hgl, const float* __restrict__ E1,
            const float* __restrict__ E2, const float* __restrict__ PQG,
            const float* __restrict__ Wo1, const float* __restrict__ bo,
            float* __restrict__ outm) {
  __shared__ __align__(16) float Ast[32][36];
  __shared__ float Bs[32][33];
  const int tx = threadIdx.x & 31, ty = threadIdx.x >> 5;
  const int bm = blockIdx.y * 32, bn = blockIdx.x * 32;
  float acc[4] = {0.f, 0.f, 0.f, 0.f};
  for (int k0 = 0; k0 < 512; k0 += 32) {
    const int kp = k0 & 255;
#pragma unroll
    for (int i = 0; i < 4; ++i) {
      int idx = (int)threadIdx.x + i * 256, r = idx >> 5, c = idx & 31;
      if (k0 < 256) {
        Ast[c][r] = hgl[(bm + r) * 256 + kp + c];
        Bs[r][c] = Wo1[(kp + r) * 256 + bn + c];
      } else if (bm < 256) {
        Ast[c][r] = E2[(bm + r) * 256 + kp + c];
        Bs[r][c] = PQG[(256 + kp + r) * 512 + 256 + bn + c];
      } else {
        Ast[r][c] = E1[(kp + r) * 256 + (bm - 256) + c];
        Bs[r][c] = PQG[(kp + r) * 512 + 256 + bn + c];
      }
    }
    __syncthreads();
#pragma unroll
    for (int kk = 0; kk < 32; ++kk) {
      const float4 a4 = *reinterpret_cast<const float4*>(&Ast[kk][4 * ty]);
      const float bv = Bs[kk][tx];
      acc[0] = fmaf(a4.x, bv, acc[0]);
      acc[1] = fmaf(a4.y, bv, acc[1]);
      acc[2] = fmaf(a4.z, bv, acc[2]);
      acc[3] = fmaf(a4.w, bv, acc[3]);
    }
    __syncthreads();
  }
  const float bias = bo[bn + tx];
#pragma unroll
  for (int i = 0; i < 4; ++i) {
    const float vv = acc[i] + bias;
    outm[(bm + 4 * ty + i) * 256 + bn + tx] = vv > 0.f ? vv : 0.f;
  }
}

// ---------------------------------------------------------------------------
// K6: cos (+norms fused) + final score MLP -> Mblk = exp(5*score).
__global__ __launch_bounds__(256)
void k6_score(const float* __restrict__ outm, const float* __restrict__ iou1,
              const float* __restrict__ Wf1, const float* __restrict__ bf1,
              const float* __restrict__ Wf2, const float* __restrict__ bf2,
              float* __restrict__ Mblk) {
  const int tid = threadIdx.x;
  const int s = blockIdx.x;
  __shared__ __align__(16) float so[256];
  so[tid] = outm[s * 256 + tid];
  __syncthreads();
  const float* od = outm + (256 + tid) * 256;
  float dot = 0.f, na2 = 0.f, nb2 = 0.f;
#pragma unroll 8
  for (int j = 0; j < 256; j += 4) {
    const float4 o4 = *reinterpret_cast<const float4*>(od + j);
    const float4 s4 = *reinterpret_cast<const float4*>(&so[j]);
    dot = fmaf(s4.x, o4.x, dot); dot = fmaf(s4.y, o4.y, dot);
    dot = fmaf(s4.z, o4.z, dot); dot = fmaf(s4.w, o4.w, dot);
    na2 = fmaf(s4.x, s4.x, na2); na2 = fmaf(s4.y, s4.y, na2);
    na2 = fmaf(s4.z, s4.z, na2); na2 = fmaf(s4.w, s4.w, na2);
    nb2 = fmaf(o4.x, o4.x, nb2); nb2 = fmaf(o4.y, o4.y, nb2);
    nb2 = fmaf(o4.z, o4.z, nb2); nb2 = fmaf(o4.w, o4.w, nb2);
  }
  const float na = fmaxf(sqrtf(na2), 1e-6f);
  const float nb = fmaxf(sqrtf(nb2), 1e-6f);
  const float cosv = dot / (na * nb);
  const float i1 = iou1[s * 256 + tid];
  float sz = 0.f;
#pragma unroll
  for (int m = 0; m < 8; ++m) {
    float hm = fmaf(cosv, Wf1[m], fmaf(i1, Wf1[8 + m], bf1[m]));
    hm = hm > 0.f ? hm : 0.f;
    sz = fmaf(hm, Wf2[m], sz);
  }
  const float score = sigmoidf_(sz + bf2[0]);
  Mblk[s * 256 + tid] = expf(5.0f * score);
}

// ---------------------------------------------------------------------------
// K7: Sinkhorn, single 1024-thread block. M register-resident ONCE (row layout,
// fp16 half2: lane owns cols 4l..4l+3 for its wave's 16 rows). Column partials
// come from the same registers (per-lane over its 16 rows), reduced across the
// 16 waves via psum[16][260] in LDS. ~90 VGPR -> no spill at 16 waves/CU.
__global__ __launch_bounds__(1024)
void k7_sink(const float* __restrict__ Mg, float* __restrict__ outp) {
  __shared__ __align__(16) float su_f[256];
  __shared__ __align__(16) float svs_f[256];   // 256*sv
  __shared__ __align__(16) float psum[16][260];
  __shared__ float wsumU[16], wsumV[4];
  const int tid = threadIdx.x, w = tid >> 6, l = tid & 63;
  const float slack = 2.71828182845904523536f;  // exp(LAM*SLACK) = exp(1)
  const float INV256 = 0.00390625f;
  const int rev = ((l & 1) << 3) | ((l & 2) << 1) | ((l & 4) >> 1) | ((l & 8) >> 3);
  const bool b0 = l & 1, b1 = l & 2, b2 = l & 4, b3 = l & 8;

  // stage M rows -> fp16 registers
  h2t mrA[16], mrB[16];
#pragma unroll
  for (int i = 0; i < 16; ++i) {
    const float4 f = *reinterpret_cast<const float4*>(Mg + (w * 16 + i) * 256 + 4 * l);
    mrA[i] = pack2(f.x, f.y);
    mrB[i] = pack2(f.z, f.w);
  }
  if (tid < 256) svs_f[tid] = 256.0f;
  __syncthreads();

  float sv256 = 1.0f;
  for (int it = 0; it < 8; ++it) {
    // ---- slack-row scalar from previous sv generation
    const float sv_tot =
        (it == 0) ? 257.0f : (wsumV[0] + wsumV[1] + wsumV[2] + wsumV[3] + sv256);
    const float su256 = 1.0f / (slack * sv_tot);
    // ---- row pass: S = 256 * rowsum; su = 1/(rowsum + slack*sv256)
    const float4 va = *reinterpret_cast<const float4*>(&svs_f[4 * l]);
    const h2t sva = pack2(va.x, va.y), svb = pack2(va.z, va.w);
    float p[16];
#pragma unroll
    for (int i = 0; i < 16; ++i) p[i] = fdot2f(mrA[i], sva, fdot2f(mrB[i], svb, 0.0f));
#pragma unroll
    for (int i = 0; i < 8; ++i) {
      const float keep = b0 ? p[i + 8] : p[i], give = b0 ? p[i] : p[i + 8];
      p[i] = keep + dpp_get<0xB1>(give);
    }
#pragma unroll
    for (int i = 0; i < 4; ++i) {
      const float keep = b1 ? p[i + 4] : p[i], give = b1 ? p[i] : p[i + 4];
      p[i] = keep + dpp_get<0x4E>(give);
    }
#pragma unroll
    for (int i = 0; i < 2; ++i) {
      const float keep = b2 ? p[i + 2] : p[i], give = b2 ? p[i] : p[i + 2];
      p[i] = keep + dpp_get<0x141>(give);
    }
    {
      const float keep = b3 ? p[1] : p[0], give = b3 ? p[0] : p[1];
      p[0] = keep + dpp_get<0x140>(give);
    }
    float S = p[0];
    S += swz_get<0x401F>(S);
    S += __shfl_xor(S, 32, 64);
    const float su_val = 1.0f / (S * INV256 + slack * sv256);
    if (l < 16) su_f[w * 16 + rev] = su_val;
    const float wsU = allred16(su_val);  // lanes 0-15 hold the 16 distinct su
    if (l == 0) wsumU[w] = wsU;
    __syncthreads();
    // ---- col pass from row regs: pc[j] partial for col 4l+j over wave's rows
    float su16[16];
#pragma unroll
    for (int k = 0; k < 16; k += 4) {
      const float4 t = *reinterpret_cast<const float4*>(&su_f[w * 16 + k]);
      su16[k] = t.x; su16[k + 1] = t.y; su16[k + 2] = t.z; su16[k + 3] = t.w;
    }
    float pc0 = 0.f, pc1 = 0.f, pc2 = 0.f, pc3 = 0.f;
#pragma unroll
    for (int i = 0; i < 16; ++i) {
      const float ui = su16[i];
      pc0 = fmaf((float)mrA[i].x, ui, pc0);
      pc1 = fmaf((float)mrA[i].y, ui, pc1);
      pc2 = fmaf((float)mrB[i].x, ui, pc2);
      pc3 = fmaf((float)mrB[i].y, ui, pc3);
    }
    float4 pcv; pcv.x = pc0; pcv.y = pc1; pcv.z = pc2; pcv.w = pc3;
    *reinterpret_cast<float4*>(&psum[w][4 * l]) = pcv;
    __syncthreads();
    // ---- sv phase (waves 0..3): colsum + slack*su256
    const float su_tot = wsumU[0] + wsumU[1] + wsumU[2] + wsumU[3] + wsumU[4] +
                         wsumU[5] + wsumU[6] + wsumU[7] + wsumU[8] + wsumU[9] +
                         wsumU[10] + wsumU[11] + wsumU[12] + wsumU[13] +
                         wsumU[14] + wsumU[15] + su256;
    if (tid < 256) {
      float cs = 0.f;
#pragma unroll
      for (int g = 0; g < 16; ++g) cs += psum[g][tid];
      const float sv_val = 1.0f / (cs + slack * su256);
      svs_f[tid] = 256.0f * sv_val;
      float t = allred16(sv_val);
      t += swz_get<0x401F>(t);
      t += __shfl_xor(t, 32, 64);
      if (l == 0) wsumV[w] = t;
    }
    sv256 = 1.0f / (slack * su_tot);
    __syncthreads();
  }
  // ---- output: out[r][c] = su[r] * M[r][c] * sv[c]   (svs = 256*sv)
  const float4 sv4 = *reinterpret_cast<const float4*>(&svs_f[4 * l]);
#pragma unroll
  for (int i = 0; i < 16; ++i) {
    const float uo = su_f[w * 16 + i] * INV256;
    float4 o;
    o.x = uo * (float)mrA[i].x * sv4.x;
    o.y = uo * (float)mrA[i].y * sv4.y;
    o.z = uo * (float)mrB[i].x * sv4.z;
    o.w = uo * (float)mrB[i].y * sv4.w;
    *reinterpret_cast<float4*>(outp + (w * 16 + i) * 256 + 4 * l) = o;
  }
}

// ---------------------------------------------------------------------------
extern "C" void kernel_launch(void* const* d_in, const int* in_sizes, int n_in,
                              void* d_out, int out_size, void* d_ws, size_t ws_size,
                              hipStream_t stream) {
  (void)in_sizes; (void)n_in; (void)out_size; (void)ws_size;
  const float* x      = (const float*)d_in[0];
  const float* coords = (const float*)d_in[1];
  const float* co     = (const float*)d_in[2];
  // d_in[3] = edge_index (int32) — structure is deterministic, not needed
  const float* Wc    = (const float*)d_in[4];
  const float* bc    = (const float*)d_in[5];
  const float* Wapp1 = (const float*)d_in[6];
  const float* bapp1 = (const float*)d_in[7];
  const float* Wapp2 = (const float*)d_in[8];
  const float* bapp2 = (const float*)d_in[9];
  const float* Wg1   = (const float*)d_in[10];
  const float* bg1   = (const float*)d_in[11];
  const float* Wg2   = (const float*)d_in[12];
  const float* bg2   = (const float*)d_in[13];
  const float* Wa1   = (const float*)d_in[14];
  const float* ba1   = (const float*)d_in[15];
  const float* Wa2   = (const float*)d_in[16];
  const float* ba2   = (const float*)d_in[17];
  const float* Wo1   = (const float*)d_in[18];
  const float* Wo2   = (const float*)d_in[19];
  const float* bo    = (const float*)d_in[20];
  const float* Wf1   = (const float*)d_in[21];
  const float* bf1   = (const float*)d_in[22];
  const float* Wf2   = (const float*)d_in[23];
  const float* bf2   = (const float*)d_in[24];

  float* ws   = (float*)d_ws;
  float* h    = ws + 0;        // 512*256
  float* PQG  = ws + 131072;   // 512*512
  float* E1   = ws + 393216;   // 256*256
  float* E2   = ws + 458752;   // 256*256
  float* iou1 = ws + 524288;   // 256*256
  float* outm = ws + 589824;   // 512*256
  float* Mblk = ws + 720896;   // 256*256

  k1_h<<<dim3(8, 16), 256, 0, stream>>>(x, Wc, bc, h);
  k2_pqg<<<dim3(16, 16), 256, 0, stream>>>(h, Wapp1, bapp1, Wo2, PQG);
  k3_edges<<<512, 256, 0, stream>>>(PQG, coords, co, Wapp2, bapp2, Wg1, bg1, Wg2,
                                    bg2, Wa1, ba1, Wa2, ba2, E1, E2, iou1);
  k5_out<<<dim3(8, 16), 256, 0, stream>>>(h, E1, E2, PQG, Wo1, bo, outm);
  k6_score<<<256, 256, 0, stream>>>(outm, iou1, Wf1, bf1, Wf2, bf2, Mblk);
  k7_sink<<<1, 1024, 0, stream>>>(Mblk, (float*)d_out);
}

// Round 6
// 96.002 us; speedup vs baseline: 2.4144x; 1.0941x over previous
//
#include <hip/hip_runtime.h>
#include <math.h>

// completeNet: graph-net + Sinkhorn, fully factorized.
// T=256 tracks (nodes 0..255), M=256 dets (nodes 256..511), D_IN=512, D_EMB=256.
// GEMMs (k1/k2/k5): 32x32 tile, A in LDS (transposed, dbuf, 1 barrier/step),
// B streamed from L2 into per-thread registers (column-stationary, dbuf).

__device__ __forceinline__ float sigmoidf_(float x) { return 1.0f / (1.0f + expf(-x)); }

typedef _Float16 h2t __attribute__((ext_vector_type(2)));

__device__ __forceinline__ h2t pack2(float x, float y) {
  h2t r; r.x = (_Float16)x; r.y = (_Float16)y; return r;
}
__device__ __forceinline__ float fdot2f(h2t a, h2t b, float c) {
  return __builtin_amdgcn_fdot2(a, b, c, false);
}
template <int CTRL>
__device__ __forceinline__ float dpp_get(float x) {
  return __builtin_bit_cast(
      float, __builtin_amdgcn_mov_dpp(__builtin_bit_cast(int, x), CTRL, 0xF, 0xF, false));
}
template <int IMM>
__device__ __forceinline__ float swz_get(float x) {
  return __builtin_bit_cast(
      float, __builtin_amdgcn_ds_swizzle(__builtin_bit_cast(int, x), IMM));
}
__device__ __forceinline__ float allred16(float x) {
  x += dpp_get<0xB1>(x);   // xor1
  x += dpp_get<0x4E>(x);   // xor2
  x += dpp_get<0x141>(x);  // xor7
  x += dpp_get<0x140>(x);  // xor15
  return x;
}

// ---------------------------------------------------------------------------
// K1: h = relu(x @ W_cnn + b_cnn)   (512x512)@(512x256), grid (8,16)
__global__ __launch_bounds__(256)
void k1_h(const float* __restrict__ x, const float* __restrict__ Wc,
          const float* __restrict__ bc, float* __restrict__ h) {
  __shared__ __align__(16) float Ast[2][32][36];
  const int tid = threadIdx.x;
  const int tx = tid & 31, ty = tid >> 5;        // out col tx, rows 4ty..4ty+3
  const int ar = tid >> 3, ac = (tid & 7) * 4;   // A-load: row ar, cols ac..ac+3
  const int bm = blockIdx.y * 32, bn = blockIdx.x * 32;
  const float* __restrict__ Bp = Wc + bn + tx;   // column bn+tx, stride 256
  const float* __restrict__ Ap = x + (bm + ar) * 512 + ac;

  float4 aA, aB;
  float bA[32], bB[32];
  float acc[4] = {0.f, 0.f, 0.f, 0.f};

#define K1_LOAD(T, AREG, BARR)                                         \
  {                                                                    \
    AREG = *reinterpret_cast<const float4*>(Ap + (T) * 32);            \
    _Pragma("unroll") for (int kk = 0; kk < 32; ++kk)                  \
        BARR[kk] = Bp[((T) * 32 + kk) * 256];                          \
  }
#define K1_STORE(BUF, AREG)                                            \
  {                                                                    \
    Ast[BUF][ac + 0][ar] = AREG.x; Ast[BUF][ac + 1][ar] = AREG.y;      \
    Ast[BUF][ac + 2][ar] = AREG.z; Ast[BUF][ac + 3][ar] = AREG.w;      \
  }
#define K1_COMP(BUF, BARR)                                             \
  {                                                                    \
    _Pragma("unroll") for (int kk = 0; kk < 32; ++kk) {                \
      const float4 a4 =                                                \
          *reinterpret_cast<const float4*>(&Ast[BUF][kk][4 * ty]);     \
      const float bv = BARR[kk];                                       \
      acc[0] = fmaf(a4.x, bv, acc[0]); acc[1] = fmaf(a4.y, bv, acc[1]);\
      acc[2] = fmaf(a4.z, bv, acc[2]); acc[3] = fmaf(a4.w, bv, acc[3]);\
    }                                                                  \
  }

  K1_LOAD(0, aA, bA);
  K1_STORE(0, aA);
  __syncthreads();
  for (int t = 0; t < 16; t += 2) {
    K1_LOAD(t + 1, aB, bB);
    K1_COMP(0, bA);
    K1_STORE(1, aB);
    __syncthreads();
    if (t + 2 < 16) { K1_LOAD(t + 2, aA, bA); }
    K1_COMP(1, bB);
    if (t + 2 < 16) { K1_STORE(0, aA); }
    __syncthreads();
  }
  const float bias = bc[bn + tx];
#pragma unroll
  for (int i = 0; i < 4; ++i) {
    const float vv = acc[i] + bias;
    h[(bm + 4 * ty + i) * 256 + bn + tx] = vv > 0.f ? vv : 0.f;
  }
#undef K1_LOAD
#undef K1_STORE
#undef K1_COMP
}

// ---------------------------------------------------------------------------
// K2: PQG (512x512): j<128 P = h@W1[:256]+bapp1; j<256 Q = h@W1[256:]; else G = h@Wo2
// grid (16,16)
__global__ __launch_bounds__(256)
void k2_pqg(const float* __restrict__ h, const float* __restrict__ W1,
            const float* __restrict__ b1, const float* __restrict__ Wo2,
            float* __restrict__ PQG) {
  __shared__ __align__(16) float Ast[2][32][36];
  const int tid = threadIdx.x;
  const int tx = tid & 31, ty = tid >> 5;
  const int ar = tid >> 3, ac = (tid & 7) * 4;
  const int bm = blockIdx.y * 32, bn = blockIdx.x * 32;
  const int col = bn + tx;
  const float* __restrict__ Bp;
  int ldb;
  if (bn < 128)      { Bp = W1 + col; ldb = 128; }
  else if (bn < 256) { Bp = W1 + 256 * 128 + (col - 128); ldb = 128; }
  else               { Bp = Wo2 + (col - 256); ldb = 256; }
  const float* __restrict__ Ap = h + (bm + ar) * 256 + ac;

  float4 aA, aB;
  float bA[32], bB[32];
  float acc[4] = {0.f, 0.f, 0.f, 0.f};

#define K2_LOAD(T, AREG, BARR)                                         \
  {                                                                    \
    AREG = *reinterpret_cast<const float4*>(Ap + (T) * 32);            \
    _Pragma("unroll") for (int kk = 0; kk < 32; ++kk)                  \
        BARR[kk] = Bp[((T) * 32 + kk) * ldb];                          \
  }
#define K2_STORE(BUF, AREG)                                            \
  {                                                                    \
    Ast[BUF][ac + 0][ar] = AREG.x; Ast[BUF][ac + 1][ar] = AREG.y;      \
    Ast[BUF][ac + 2][ar] = AREG.z; Ast[BUF][ac + 3][ar] = AREG.w;      \
  }
#define K2_COMP(BUF, BARR)                                             \
  {                                                                    \
    _Pragma("unroll") for (int kk = 0; kk < 32; ++kk) {                \
      const float4 a4 =                                                \
          *reinterpret_cast<const float4*>(&Ast[BUF][kk][4 * ty]);     \
      const float bv = BARR[kk];                                       \
      acc[0] = fmaf(a4.x, bv, acc[0]); acc[1] = fmaf(a4.y, bv, acc[1]);\
      acc[2] = fmaf(a4.z, bv, acc[2]); acc[3] = fmaf(a4.w, bv, acc[3]);\
    }                                                                  \
  }

  K2_LOAD(0, aA, bA);
  K2_STORE(0, aA);
  __syncthreads();
  for (int t = 0; t < 8; t += 2) {
    K2_LOAD(t + 1, aB, bB);
    K2_COMP(0, bA);
    K2_STORE(1, aB);
    __syncthreads();
    if (t + 2 < 8) { K2_LOAD(t + 2, aA, bA); }
    K2_COMP(1, bB);
    if (t + 2 < 8) { K2_STORE(0, aA); }
    __syncthreads();
  }
  const float bias = (bn < 128) ? b1[col] : 0.f;
#pragma unroll
  for (int i = 0; i < 4; ++i)
    PQG[(bm + 4 * ty + i) * 512 + col] = acc[i] + bias;
#undef K2_LOAD
#undef K2_STORE
#undef K2_COMP
}

// ---------------------------------------------------------------------------
// K3: per-edge app/geo/e. blocks 0..255 = half0 (track fixed), 256..511 = half1.
__global__ __launch_bounds__(256)
void k3_edges(const float* __restrict__ PQG, const float* __restrict__ coords,
              const float* __restrict__ co, const float* __restrict__ Wapp2,
              const float* __restrict__ bapp2, const float* __restrict__ Wg1,
              const float* __restrict__ bg1, const float* __restrict__ Wg2,
              const float* __restrict__ bg2, const float* __restrict__ Wa1,
              const float* __restrict__ ba1, const float* __restrict__ Wa2,
              const float* __restrict__ ba2, float* __restrict__ E1,
              float* __restrict__ E2, float* __restrict__ iou1) {
  __shared__ __align__(16) float sFix[128], sW2[128], sWg1[256], sGfix[32], sWg2[32];
  __shared__ float sWa1[16], sBa1[8], sWa2[8];
  const int tid = threadIdx.x;
  const int half = blockIdx.x >> 8;
  const int fr = blockIdx.x & 255;
  if (tid < 128) {
    sFix[tid] = PQG[fr * 512 + (half ? 128 + tid : tid)];
    sW2[tid] = Wapp2[tid];
  }
  sWg1[tid] = Wg1[tid & 255];
  if (tid < 32) sWg2[tid] = Wg2[tid];
  if (tid < 16) sWa1[tid] = Wa1[tid];
  if (tid < 8) { sBa1[tid] = ba1[tid]; sWa2[tid] = Wa2[tid]; }
  __syncthreads();
  if (tid < 32) {
    const int offf = half ? 4 : 0;
    float g = bg1[tid];
#pragma unroll
    for (int q = 0; q < 4; ++q) g = fmaf(coords[fr * 4 + q], sWg1[(offf + q) * 32 + tid], g);
    sGfix[tid] = g;
  }
  __syncthreads();

  const int d = tid;
  const int pnode = 256 + d;
  const float* tb = PQG + pnode * 512 + (half ? 0 : 128);
  float z = 0.f;
#pragma unroll
  for (int j = 0; j < 128; j += 4) {
    const float4 q4 = *reinterpret_cast<const float4*>(tb + j);
    const float4 pf = *reinterpret_cast<const float4*>(&sFix[j]);
    const float4 w4 = *reinterpret_cast<const float4*>(&sW2[j]);
    float a;
    a = pf.x + q4.x; a = a > 0.f ? a : 0.f; z = fmaf(a, w4.x, z);
    a = pf.y + q4.y; a = a > 0.f ? a : 0.f; z = fmaf(a, w4.y, z);
    a = pf.z + q4.z; a = a > 0.f ? a : 0.f; z = fmaf(a, w4.z, z);
    a = pf.w + q4.w; a = a > 0.f ? a : 0.f; z = fmaf(a, w4.w, z);
  }
  const float app = sigmoidf_(z + bapp2[0]);
  const float4 cp = *reinterpret_cast<const float4*>(coords + pnode * 4);
  const int offp = half ? 0 : 4;
  float gz = 0.f;
#pragma unroll
  for (int mb = 0; mb < 8; ++mb) {
    const float4 g4 = *reinterpret_cast<const float4*>(&sGfix[4 * mb]);
    const float4 w0 = *reinterpret_cast<const float4*>(&sWg1[(offp + 0) * 32 + 4 * mb]);
    const float4 w1 = *reinterpret_cast<const float4*>(&sWg1[(offp + 1) * 32 + 4 * mb]);
    const float4 w2 = *reinterpret_cast<const float4*>(&sWg1[(offp + 2) * 32 + 4 * mb]);
    const float4 w3 = *reinterpret_cast<const float4*>(&sWg1[(offp + 3) * 32 + 4 * mb]);
    const float4 v2 = *reinterpret_cast<const float4*>(&sWg2[4 * mb]);
    float hm;
    hm = g4.x + cp.x * w0.x + cp.y * w1.x + cp.z * w2.x + cp.w * w3.x;
    hm = hm > 0.f ? hm : 0.f; gz = fmaf(hm, v2.x, gz);
    hm = g4.y + cp.x * w0.y + cp.y * w1.y + cp.z * w2.y + cp.w * w3.y;
    hm = hm > 0.f ? hm : 0.f; gz = fmaf(hm, v2.y, gz);
    hm = g4.z + cp.x * w0.z + cp.y * w1.z + cp.z * w2.z + cp.w * w3.z;
    hm = hm > 0.f ? hm : 0.f; gz = fmaf(hm, v2.z, gz);
    hm = g4.w + cp.x * w0.w + cp.y * w1.w + cp.z * w2.w + cp.w * w3.w;
    hm = hm > 0.f ? hm : 0.f; gz = fmaf(hm, v2.w, gz);
  }
  const float geo = sigmoidf_(gz + bg2[0]);
  float ez = 0.f;
#pragma unroll
  for (int m = 0; m < 8; ++m) {
    float hm = fmaf(app, sWa1[m], fmaf(geo, sWa1[8 + m], sBa1[m]));
    hm = hm > 0.f ? hm : 0.f;
    ez = fmaf(hm, sWa2[m], ez);
  }
  const float e = sigmoidf_(ez + ba2[0]);
  if (half == 0) {
    E1[fr * 256 + d] = e;
    const float4 A4 = *reinterpret_cast<const float4*>(co + fr * 4);
    const float4 B4 = *reinterpret_cast<const float4*>(co + pnode * 4);
    const float ix1 = fmaxf(A4.x, B4.x), iy1 = fmaxf(A4.y, B4.y);
    const float ix2 = fminf(A4.z, B4.z), iy2 = fminf(A4.w, B4.w);
    const float inter = fmaxf(ix2 - ix1, 0.f) * fmaxf(iy2 - iy1, 0.f);
    const float areaA = (A4.z - A4.x) * (A4.w - A4.y);
    const float areaB = (B4.z - B4.x) * (B4.w - B4.y);
    iou1[fr * 256 + d] = inter / (areaA + areaB - inter + 1e-8f);
  } else {
    E2[fr * 256 + d] = e;
  }
}

// ---------------------------------------------------------------------------
// K5: out = relu(h@Wo1 + E@G + bo), grid (8,16). t<8: h@Wo1. t>=8: E-GEMM.
__global__ __launch_bounds__(256)
void k5_out(const float* __restrict__ hgl, const float* __restrict__ E1,
            const float* __restrict__ E2, const float* __restrict__ PQG,
            const float* __restrict__ Wo1, const float* __restrict__ bo,
            float* __restrict__ outm) {
  __shared__ __align__(16) float Ast[2][32][36];
  const int tid = threadIdx.x;
  const int tx = tid & 31, ty = tid >> 5;
  const int ar = tid >> 3, ac = (tid & 7) * 4;
  const int bm = blockIdx.y * 32, bn = blockIdx.x * 32;
  const int col = bn + tx;
  const bool detrows = (bm >= 256);
  // phase-1 pointers
  const float* __restrict__ Ap1 = hgl + (bm + ar) * 256 + ac;
  const float* __restrict__ Bp1 = Wo1 + col;
  // phase-2 pointers
  const float* __restrict__ Ap2 = detrows
      ? (E1 + ar * 256 + (bm - 256) + ac)        // direct: Ast[k][m]
      : (E2 + (bm + ar) * 256 + ac);             // transposed store
  const float* __restrict__ Bp2 = PQG + (detrows ? 0 : 256 * 512) + 256 + col;

  float4 aA, aB;
  float bA[32], bB[32];
  float acc[4] = {0.f, 0.f, 0.f, 0.f};

#define K5_LOAD(T, AREG, BARR)                                          \
  {                                                                     \
    if ((T) < 8) {                                                      \
      AREG = *reinterpret_cast<const float4*>(Ap1 + (T) * 32);          \
      _Pragma("unroll") for (int kk = 0; kk < 32; ++kk)                 \
          BARR[kk] = Bp1[((T) * 32 + kk) * 256];                        \
    } else {                                                            \
      const int tk = (T) - 8;                                           \
      AREG = *reinterpret_cast<const float4*>(                          \
          Ap2 + tk * 32 * (detrows ? 256 : 1));                         \
      _Pragma("unroll") for (int kk = 0; kk < 32; ++kk)                 \
          BARR[kk] = Bp2[(tk * 32 + kk) * 512];                         \
    }                                                                   \
  }
#define K5_STORE(T, BUF, AREG)                                          \
  {                                                                     \
    if ((T) >= 8 && detrows) {                                          \
      *reinterpret_cast<float4*>(&Ast[BUF][ar][ac]) = AREG;             \
    } else {                                                            \
      Ast[BUF][ac + 0][ar] = AREG.x; Ast[BUF][ac + 1][ar] = AREG.y;     \
      Ast[BUF][ac + 2][ar] = AREG.z; Ast[BUF][ac + 3][ar] = AREG.w;     \
    }                                                                   \
  }
#define K5_COMP(BUF, BARR)                                              \
  {                                                                     \
    _Pragma("unroll") for (int kk = 0; kk < 32; ++kk) {                 \
      const float4 a4 =                                                 \
          *reinterpret_cast<const float4*>(&Ast[BUF][kk][4 * ty]);      \
      const float bv = BARR[kk];                                        \
      acc[0] = fmaf(a4.x, bv, acc[0]); acc[1] = fmaf(a4.y, bv, acc[1]); \
      acc[2] = fmaf(a4.z, bv, acc[2]); acc[3] = fmaf(a4.w, bv, acc[3]); \
    }                                                                   \
  }

  K5_LOAD(0, aA, bA);
  K5_STORE(0, 0, aA);
  __syncthreads();
  for (int t = 0; t < 16; t += 2) {
    K5_LOAD(t + 1, aB, bB);
    K5_COMP(0, bA);
    K5_STORE(t + 1, 1, aB);
    __syncthreads();
    if (t + 2 < 16) { K5_LOAD(t + 2, aA, bA); }
    K5_COMP(1, bB);
    if (t + 2 < 16) { K5_STORE(t + 2, 0, aA); }
    __syncthreads();
  }
  const float bias = bo[col];
#pragma unroll
  for (int i = 0; i < 4; ++i) {
    const float vv = acc[i] + bias;
    outm[(bm + 4 * ty + i) * 256 + col] = vv > 0.f ? vv : 0.f;
  }
#undef K5_LOAD
#undef K5_STORE
#undef K5_COMP
}

// ---------------------------------------------------------------------------
// K6: cos (+norms fused) + final score MLP -> Mblk = exp(5*score).
__global__ __launch_bounds__(256)
void k6_score(const float* __restrict__ outm, const float* __restrict__ iou1,
              const float* __restrict__ Wf1, const float* __restrict__ bf1,
              const float* __restrict__ Wf2, const float* __restrict__ bf2,
              float* __restrict__ Mblk) {
  const int tid = threadIdx.x;
  const int s = blockIdx.x;
  __shared__ __align__(16) float so[256];
  so[tid] = outm[s * 256 + tid];
  __syncthreads();
  const float* od = outm + (256 + tid) * 256;
  float dot = 0.f, na2 = 0.f, nb2 = 0.f;
#pragma unroll 8
  for (int j = 0; j < 256; j += 4) {
    const float4 o4 = *reinterpret_cast<const float4*>(od + j);
    const float4 s4 = *reinterpret_cast<const float4*>(&so[j]);
    dot = fmaf(s4.x, o4.x, dot); dot = fmaf(s4.y, o4.y, dot);
    dot = fmaf(s4.z, o4.z, dot); dot = fmaf(s4.w, o4.w, dot);
    na2 = fmaf(s4.x, s4.x, na2); na2 = fmaf(s4.y, s4.y, na2);
    na2 = fmaf(s4.z, s4.z, na2); na2 = fmaf(s4.w, s4.w, na2);
    nb2 = fmaf(o4.x, o4.x, nb2); nb2 = fmaf(o4.y, o4.y, nb2);
    nb2 = fmaf(o4.z, o4.z, nb2); nb2 = fmaf(o4.w, o4.w, nb2);
  }
  const float na = fmaxf(sqrtf(na2), 1e-6f);
  const float nb = fmaxf(sqrtf(nb2), 1e-6f);
  const float cosv = dot / (na * nb);
  const float i1 = iou1[s * 256 + tid];
  float sz = 0.f;
#pragma unroll
  for (int m = 0; m < 8; ++m) {
    float hm = fmaf(cosv, Wf1[m], fmaf(i1, Wf1[8 + m], bf1[m]));
    hm = hm > 0.f ? hm : 0.f;
    sz = fmaf(hm, Wf2[m], sz);
  }
  const float score = sigmoidf_(sz + bf2[0]);
  Mblk[s * 256 + tid] = expf(5.0f * score);
}

// ---------------------------------------------------------------------------
// K7: Sinkhorn, single 1024-thread block, M register-resident (row layout fp16).
// 2 barriers/iter (same-wave su_f readback uses lgkmcnt wait, not a barrier).
__global__ __launch_bounds__(1024)
void k7_sink(const float* __restrict__ Mg, float* __restrict__ outp) {
  __shared__ __align__(16) float su_f[256];
  __shared__ __align__(16) float svs_f[256];   // 256*sv
  __shared__ __align__(16) float psum[16][260];
  __shared__ float wsumU[16], wsumV[4];
  const int tid = threadIdx.x, w = tid >> 6, l = tid & 63;
  const float slack = 2.71828182845904523536f;  // exp(LAM*SLACK) = exp(1)
  const float INV256 = 0.00390625f;
  const int rev = ((l & 1) << 3) | ((l & 2) << 1) | ((l & 4) >> 1) | ((l & 8) >> 3);
  const bool b0 = l & 1, b1 = l & 2, b2 = l & 4, b3 = l & 8;

  h2t mrA[16], mrB[16];
#pragma unroll
  for (int i = 0; i < 16; ++i) {
    const float4 f = *reinterpret_cast<const float4*>(Mg + (w * 16 + i) * 256 + 4 * l);
    mrA[i] = pack2(f.x, f.y);
    mrB[i] = pack2(f.z, f.w);
  }
  if (tid < 256) svs_f[tid] = 256.0f;
  __syncthreads();

  float sv256 = 1.0f;
  for (int it = 0; it < 8; ++it) {
    const float sv_tot =
        (it == 0) ? 257.0f : (wsumV[0] + wsumV[1] + wsumV[2] + wsumV[3] + sv256);
    const float su256 = 1.0f / (slack * sv_tot);
    // ---- row pass
    const float4 va = *reinterpret_cast<const float4*>(&svs_f[4 * l]);
    const h2t sva = pack2(va.x, va.y), svb = pack2(va.z, va.w);
    float p[16];
#pragma unroll
    for (int i = 0; i < 16; ++i) p[i] = fdot2f(mrA[i], sva, fdot2f(mrB[i], svb, 0.0f));
#pragma unroll
    for (int i = 0; i < 8; ++i) {
      const float keep = b0 ? p[i + 8] : p[i], give = b0 ? p[i] : p[i + 8];
      p[i] = keep + dpp_get<0xB1>(give);
    }
#pragma unroll
    for (int i = 0; i < 4; ++i) {
      const float keep = b1 ? p[i + 4] : p[i], give = b1 ? p[i] : p[i + 4];
      p[i] = keep + dpp_get<0x4E>(give);
    }
#pragma unroll
    for (int i = 0; i < 2; ++i) {
      const float keep = b2 ? p[i + 2] : p[i], give = b2 ? p[i] : p[i + 2];
      p[i] = keep + dpp_get<0x141>(give);
    }
    {
      const float keep = b3 ? p[1] : p[0], give = b3 ? p[0] : p[1];
      p[0] = keep + dpp_get<0x140>(give);
    }
    float S = p[0];
    S += swz_get<0x401F>(S);
    S += __shfl_xor(S, 32, 64);
    const float su_val = 1.0f / (S * INV256 + slack * sv256);
    if (l < 16) su_f[w * 16 + rev] = su_val;
    const float wsU = allred16(su_val);
    if (l == 0) wsumU[w] = wsU;
    asm volatile("s_waitcnt lgkmcnt(0)" ::: "memory");  // same-wave su_f readback
    // ---- col partials from row regs
    float su16[16];
#pragma unroll
    for (int k = 0; k < 16; k += 4) {
      const float4 t = *reinterpret_cast<const float4*>(&su_f[w * 16 + k]);
      su16[k] = t.x; su16[k + 1] = t.y; su16[k + 2] = t.z; su16[k + 3] = t.w;
    }
    float pc0 = 0.f, pc1 = 0.f, pc2 = 0.f, pc3 = 0.f;
#pragma unroll
    for (int i = 0; i < 16; ++i) {
      const float ui = su16[i];
      pc0 = fmaf((float)mrA[i].x, ui, pc0);
      pc1 = fmaf((float)mrA[i].y, ui, pc1);
      pc2 = fmaf((float)mrB[i].x, ui, pc2);
      pc3 = fmaf((float)mrB[i].y, ui, pc3);
    }
    float4 pcv; pcv.x = pc0; pcv.y = pc1; pcv.z = pc2; pcv.w = pc3;
    *reinterpret_cast<float4*>(&psum[w][4 * l]) = pcv;
    __syncthreads();
    // ---- sv phase
    const float su_tot = wsumU[0] + wsumU[1] + wsumU[2] + wsumU[3] + wsumU[4] +
                         wsumU[5] + wsumU[6] + wsumU[7] + wsumU[8] + wsumU[9] +
                         wsumU[10] + wsumU[11] + wsumU[12] + wsumU[13] +
                         wsumU[14] + wsumU[15] + su256;
    if (tid < 256) {
      float cs = 0.f;
#pragma unroll
      for (int g = 0; g < 16; ++g) cs += psum[g][tid];
      const float sv_val = 1.0f / (cs + slack * su256);
      svs_f[tid] = 256.0f * sv_val;
      float t = allred16(sv_val);
      t += swz_get<0x401F>(t);
      t += __shfl_xor(t, 32, 64);
      if (l == 0) wsumV[w] = t;
    }
    sv256 = 1.0f / (slack * su_tot);
    __syncthreads();
  }
  // ---- output: out[r][c] = su[r] * M[r][c] * sv[c]
  const float4 sv4 = *reinterpret_cast<const float4*>(&svs_f[4 * l]);
#pragma unroll
  for (int i = 0; i < 16; ++i) {
    const float uo = su_f[w * 16 + i] * INV256;
    float4 o;
    o.x = uo * (float)mrA[i].x * sv4.x;
    o.y = uo * (float)mrA[i].y * sv4.y;
    o.z = uo * (float)mrB[i].x * sv4.z;
    o.w = uo * (float)mrB[i].y * sv4.w;
    *reinterpret_cast<float4*>(outp + (w * 16 + i) * 256 + 4 * l) = o;
  }
}

// ---------------------------------------------------------------------------
extern "C" void kernel_launch(void* const* d_in, const int* in_sizes, int n_in,
                              void* d_out, int out_size, void* d_ws, size_t ws_size,
                              hipStream_t stream) {
  (void)in_sizes; (void)n_in; (void)out_size; (void)ws_size;
  const float* x      = (const float*)d_in[0];
  const float* coords = (const float*)d_in[1];
  const float* co     = (const float*)d_in[2];
  // d_in[3] = edge_index (int32) — structure is deterministic, not needed
  const float* Wc    = (const float*)d_in[4];
  const float* bc    = (const float*)d_in[5];
  const float* Wapp1 = (const float*)d_in[6];
  const float* bapp1 = (const float*)d_in[7];
  const float* Wapp2 = (const float*)d_in[8];
  const float* bapp2 = (const float*)d_in[9];
  const float* Wg1   = (const float*)d_in[10];
  const float* bg1   = (const float*)d_in[11];
  const float* Wg2   = (const float*)d_in[12];
  const float* bg2   = (const float*)d_in[13];
  const float* Wa1   = (const float*)d_in[14];
  const float* ba1   = (const float*)d_in[15];
  const float* Wa2   = (const float*)d_in[16];
  const float* ba2   = (const float*)d_in[17];
  const float* Wo1   = (const float*)d_in[18];
  const float* Wo2   = (const float*)d_in[19];
  const float* bo    = (const float*)d_in[20];
  const float* Wf1   = (const float*)d_in[21];
  const float* bf1   = (const float*)d_in[22];
  const float* Wf2   = (const float*)d_in[23];
  const float* bf2   = (const float*)d_in[24];

  float* ws   = (float*)d_ws;
  float* h    = ws + 0;        // 512*256
  float* PQG  = ws + 131072;   // 512*512
  float* E1   = ws + 393216;   // 256*256
  float* E2   = ws + 458752;   // 256*256
  float* iou1 = ws + 524288;   // 256*256
  float* outm = ws + 589824;   // 512*256
  float* Mblk = ws + 720896;   // 256*256

  k1_h<<<dim3(8, 16), 256, 0, stream>>>(x, Wc, bc, h);
  k2_pqg<<<dim3(16, 16), 256, 0, stream>>>(h, Wapp1, bapp1, Wo2, PQG);
  k3_edges<<<512, 256, 0, stream>>>(PQG, coords, co, Wapp2, bapp2, Wg1, bg1, Wg2,
                                    bg2, Wa1, ba1, Wa2, ba2, E1, E2, iou1);
  k5_out<<<dim3(8, 16), 256, 0, stream>>>(h, E1, E2, PQG, Wo1, bo, outm);
  k6_score<<<256, 256, 0, stream>>>(outm, iou1, Wf1, bf1, Wf2, bf2, Mblk);
  k7_sink<<<1, 1024, 0, stream>>>(Mblk, (float*)d_out);
}